// Round 5
// baseline (569.339 us; speedup 1.0000x reference)
//
#include <hip/hip_runtime.h>
#include <hip/hip_bf16.h>

typedef __bf16 bf16_t;
typedef __bf16 bf16x8 __attribute__((ext_vector_type(8)));
typedef __bf16 bf16x4 __attribute__((ext_vector_type(4)));
typedef float f32x4 __attribute__((ext_vector_type(4)));

#define DI __device__ __forceinline__

DI f32x4 mfma16(bf16x8 a, bf16x8 b, f32x4 c) {
  return __builtin_amdgcn_mfma_f32_16x16x32_bf16(a, b, c, 0, 0, 0);
}

DI void gload16(const bf16_t* g, bf16_t* l) {
  __builtin_amdgcn_global_load_lds(
      (const __attribute__((address_space(1))) unsigned int*)g,
      (__attribute__((address_space(3))) unsigned int*)l, 16, 0, 0);
}

__constant__ int GEO_c[15] = {1,2,3,4,5,6,8,10,22,23,29,31,32,33,43};
__constant__ int POS_c[11] = {9,16,17,20,27,30,36,42,48,49,50};
__constant__ int SEM_c[24] = {7,11,12,13,14,15,18,19,21,24,25,26,28,34,35,37,38,39,40,41,44,45,46,47};

// ---------- prep: transpose f32 Wpc [1024][4096] -> bf16 WpcT [4096][1024] ----------
__global__ void k_transpose(const float* __restrict__ src, bf16_t* __restrict__ dst,
                            int K, int N) {
  __shared__ float s[64][65];
  int n0 = blockIdx.x * 64, k0 = blockIdx.y * 64;
  int t = threadIdx.x;
#pragma unroll
  for (int i = 0; i < 4; ++i) {
    int idx = t + i * 256; int kr = idx >> 4, seg = idx & 15;
    float4 v = *(const float4*)(src + (size_t)(k0 + kr) * N + n0 + seg * 4);
    s[kr][seg * 4 + 0] = v.x; s[kr][seg * 4 + 1] = v.y;
    s[kr][seg * 4 + 2] = v.z; s[kr][seg * 4 + 3] = v.w;
  }
  __syncthreads();
#pragma unroll
  for (int i = 0; i < 4; ++i) {
    int idx = t + i * 256; int nr = idx >> 4, seg = idx & 15;
    bf16x4 h;
    h[0] = (bf16_t)s[seg * 4 + 0][nr]; h[1] = (bf16_t)s[seg * 4 + 1][nr];
    h[2] = (bf16_t)s[seg * 4 + 2][nr]; h[3] = (bf16_t)s[seg * 4 + 3][nr];
    *(bf16x4*)(dst + (size_t)(n0 + nr) * K + k0 + seg * 4) = h;
  }
}

// ---------- prep: pack Wc*/Wv* into [64][4096] bf16 (cols 54..63 zero), bcv ----------
DI void cat_map(int j, int& which, int& sub, int& nc) {
  if (j < 15)      { which = 0; sub = j;      nc = 15; }
  else if (j < 26) { which = 1; sub = j - 15; nc = 11; }
  else if (j < 50) { which = 2; sub = j - 26; nc = 24; }
  else if (j < 54) { which = 3; sub = j - 50; nc = 4;  }
  else             { which = 4; sub = 0;      nc = 1;  }
}

__global__ void k_pack_cat(const float* __restrict__ Wc1, const float* __restrict__ Wc2,
                           const float* __restrict__ Wc3, const float* __restrict__ Wcs,
                           const float* __restrict__ Wv1, const float* __restrict__ Wv2,
                           const float* __restrict__ Wv3, const float* __restrict__ Wvs,
                           const float* __restrict__ bc1, const float* __restrict__ bc2,
                           const float* __restrict__ bc3, const float* __restrict__ bcs,
                           const float* __restrict__ bv1, const float* __restrict__ bv2,
                           const float* __restrict__ bv3, const float* __restrict__ bvs,
                           bf16_t* __restrict__ WcatT, bf16_t* __restrict__ WvcatT,
                           float* __restrict__ bcv) {
  int j = blockIdx.x, t = threadIdx.x;
  int which, sub, nc; cat_map(j, which, sub, nc);
  const float* Wc = which == 0 ? Wc1 : which == 1 ? Wc2 : which == 2 ? Wc3 : Wcs;
  const float* Wv = which == 0 ? Wv1 : which == 1 ? Wv2 : which == 2 ? Wv3 : Wvs;
  for (int i = 0; i < 16; ++i) {
    int k = t + i * 256;
    float vc = 0.f, vv = 0.f;
    if (which < 4) { vc = Wc[(size_t)k * nc + sub]; vv = Wv[(size_t)k * nc + sub]; }
    WcatT[(size_t)j * 4096 + k] = (bf16_t)vc;
    WvcatT[(size_t)j * 4096 + k] = (bf16_t)vv;
  }
  if (t == 0) {
    float b = 0.f;
    if (which < 4) {
      const float* bc = which == 0 ? bc1 : which == 1 ? bc2 : which == 2 ? bc3 : bcs;
      const float* bv = which == 0 ? bv1 : which == 1 ? bv2 : which == 2 ? bv3 : bvs;
      b = bc[sub] + bv[sub];
    }
    bcv[j] = b;
  }
}

// ---------- prep: ec f32 -> ecb bf16 ----------
__global__ __launch_bounds__(256) void k_ec(const float* __restrict__ ec,
                                            bf16_t* __restrict__ ecb) {
  size_t i = ((size_t)blockIdx.x * 256 + threadIdx.x) * 8;
  float4 a = *(const float4*)(ec + i), b = *(const float4*)(ec + i + 4);
  bf16x8 h;
  h[0] = (bf16_t)a.x; h[1] = (bf16_t)a.y; h[2] = (bf16_t)a.z; h[3] = (bf16_t)a.w;
  h[4] = (bf16_t)b.x; h[5] = (bf16_t)b.y; h[6] = (bf16_t)b.z; h[7] = (bf16_t)b.w;
  *(bf16x8*)(ecb + i) = h;
}

// ---------- prep: W1T[n][k] = sum_j WpcT[n, joff+j] * Wpe[k, joff+j] ----------
__global__ __launch_bounds__(256) void k_w12(const bf16_t* __restrict__ WpcT,
                                             const float* __restrict__ Wpe,
                                             bf16_t* __restrict__ W1T,
                                             bf16_t* __restrict__ W2T) {
  __shared__ bf16_t sA[128 * 64];
  __shared__ bf16_t sB[128 * 64];
  const int t = threadIdx.x, w = t >> 6, l = t & 63;
  const int lrow = l & 15, lkB = (l >> 4) << 4;
  const int k0 = blockIdx.x * 128, n0 = blockIdx.y * 128;
  const int joff = blockIdx.z * 512;
  bf16_t* dst = blockIdx.z ? W2T : W1T;

  f32x4 acc[2][8];
#pragma unroll
  for (int rf = 0; rf < 2; ++rf)
#pragma unroll
    for (int cf = 0; cf < 8; ++cf) { f32x4 z = {0.f, 0.f, 0.f, 0.f}; acc[rf][cf] = z; }

  for (int jj = 0; jj < 512; jj += 64) {
    __syncthreads();
#pragma unroll
    for (int i = 0; i < 4; ++i) {
      int row = (t >> 3) + (i << 5), seg = t & 7;
      bf16x8 v = *(const bf16x8*)(WpcT + (size_t)(n0 + row) * 1024 + joff + jj + seg * 8);
      *(bf16x8*)((char*)sA + (row << 7) + ((seg << 4) ^ ((row & 7) << 4))) = v;
    }
#pragma unroll
    for (int i = 0; i < 8; ++i) {
      int idx = t + i * 256; int row = idx >> 4, seg = idx & 15;
      float4 v = *(const float4*)(Wpe + (size_t)(k0 + row) * 1024 + joff + jj + seg * 4);
      bf16x4 h; h[0] = (bf16_t)v.x; h[1] = (bf16_t)v.y; h[2] = (bf16_t)v.z; h[3] = (bf16_t)v.w;
      *(bf16x4*)((char*)sB + (row << 7) + ((seg << 3) ^ ((row & 7) << 4))) = h;
    }
    __syncthreads();
#pragma unroll
    for (int ks = 0; ks < 2; ++ks) {
      bf16x8 af[2], bfr[8];
#pragma unroll
      for (int rf = 0; rf < 2; ++rf) {
        int row = w * 32 + rf * 16 + lrow;
        af[rf] = *(const bf16x8*)((const char*)sA + (row << 7) + (((ks << 6) | lkB) ^ ((row & 7) << 4)));
      }
#pragma unroll
      for (int cf = 0; cf < 8; ++cf) {
        int col = cf * 16 + lrow;
        bfr[cf] = *(const bf16x8*)((const char*)sB + (col << 7) + (((ks << 6) | lkB) ^ ((col & 7) << 4)));
      }
#pragma unroll
      for (int rf = 0; rf < 2; ++rf)
#pragma unroll
        for (int cf = 0; cf < 8; ++cf)
          acc[rf][cf] = mfma16(af[rf], bfr[cf], acc[rf][cf]);
    }
  }
#pragma unroll
  for (int cf = 0; cf < 8; ++cf)
#pragma unroll
    for (int rf = 0; rf < 2; ++rf)
#pragma unroll
      for (int r = 0; r < 4; ++r) {
        int nrow = n0 + w * 32 + rf * 16 + ((l >> 4) << 2) + r;
        dst[(size_t)nrow * 512 + k0 + cf * 16 + lrow] = (bf16_t)acc[rf][cf][r];
      }
}

// ---------- prep: b12[0][n] = bpe_h . WpcT[n,:512] + bpc[n]; b12[1][n] = bpe_t . WpcT[n,512:] ----------
__global__ __launch_bounds__(256) void k_bias(const bf16_t* __restrict__ WpcT,
                                              const float* __restrict__ bpe,
                                              const float* __restrict__ bpc,
                                              float* __restrict__ b12) {
  int w = threadIdx.x >> 6, l = threadIdx.x & 63;
  int n = blockIdx.x * 4 + w;
  const bf16_t* r = WpcT + (size_t)n * 1024;
  bf16x8 v1 = *(const bf16x8*)(r + l * 8);
  bf16x8 v2 = *(const bf16x8*)(r + 512 + l * 8);
  float s1 = 0.f, s2 = 0.f;
#pragma unroll
  for (int e = 0; e < 8; ++e) {
    s1 += (float)v1[e] * bpe[l * 8 + e];
    s2 += (float)v2[e] * bpe[512 + l * 8 + e];
  }
#pragma unroll
  for (int off = 32; off; off >>= 1) {
    s1 += __shfl_down(s1, off);
    s2 += __shfl_down(s2, off);
  }
  if (l == 0) { b12[n] = s1 + bpc[n]; b12[4096 + n] = s2; }
}

// ---------- k_ht2: HU/TU = ecb @ W{1,2}T + b12 ----------
// 2-phase double-buffered: global_load_lds for tile t+1 issued BEFORE compute(t),
// counted s_waitcnt vmcnt(8) so prefetch loads stay in flight across the barrier.
__global__ __launch_bounds__(256, 2) void k_ht2(const bf16_t* __restrict__ ecb,
                                                const bf16_t* __restrict__ W1T,
                                                const bf16_t* __restrict__ W2T,
                                                const float* __restrict__ b12,
                                                bf16_t* __restrict__ HU,
                                                bf16_t* __restrict__ TU) {
  __shared__ bf16_t sA[2][128 * 64];
  __shared__ bf16_t sB[2][128 * 64];
  const int t = threadIdx.x, w = t >> 6, l = t & 63;
  const int lrow = l & 15, lkB = (l >> 4) << 4;
  const int n0 = blockIdx.x * 128, m0 = blockIdx.y * 128, z = blockIdx.z;
  const bf16_t* Bw = z ? W2T : W1T;
  const float* bias = b12 + z * 4096;
  bf16_t* dst = z ? TU : HU;

  const int srow = (w << 5) + (l >> 3);   // wave w stages rows w*32..+31
  const int sk = (l & 7) * 8;
  const bf16_t* gA = ecb + (size_t)(m0 + srow) * 512 + sk;
  const bf16_t* gB = Bw + (size_t)(n0 + srow) * 512 + sk;
  const int lofs = (w << 11);             // wave's element offset in a tile buffer

  f32x4 acc[2][8];
#pragma unroll
  for (int rf = 0; rf < 2; ++rf)
#pragma unroll
    for (int cf = 0; cf < 8; ++cf) { f32x4 zz = {0.f, 0.f, 0.f, 0.f}; acc[rf][cf] = zz; }

  // prologue: stage tile 0 into buffer 0
#pragma unroll
  for (int i = 0; i < 4; ++i) gload16(gA + i * 4096, &sA[0][lofs] + i * 512);
#pragma unroll
  for (int i = 0; i < 4; ++i) gload16(gB + i * 4096, &sB[0][lofs] + i * 512);

#pragma unroll 1
  for (int tt = 0; tt < 8; ++tt) {
    const int cur = tt & 1;
    if (tt < 7) {
      const int kk = (tt + 1) * 64;
#pragma unroll
      for (int i = 0; i < 4; ++i) gload16(gA + i * 4096 + kk, &sA[cur ^ 1][lofs] + i * 512);
#pragma unroll
      for (int i = 0; i < 4; ++i) gload16(gB + i * 4096 + kk, &sB[cur ^ 1][lofs] + i * 512);
      asm volatile("s_waitcnt vmcnt(8)" ::: "memory");   // tile tt landed; t+1 in flight
    } else {
      asm volatile("s_waitcnt vmcnt(0)" ::: "memory");
    }
    __syncthreads();
#pragma unroll
    for (int ks = 0; ks < 2; ++ks) {
      bf16x8 af[2], bfr[8];
#pragma unroll
      for (int rf = 0; rf < 2; ++rf) {
        int row = w * 32 + rf * 16 + lrow;
        af[rf] = *(const bf16x8*)((const char*)&sA[cur][0] + (row << 7) + (ks << 6) + lkB);
      }
#pragma unroll
      for (int cf = 0; cf < 8; ++cf) {
        int col = cf * 16 + lrow;
        bfr[cf] = *(const bf16x8*)((const char*)&sB[cur][0] + (col << 7) + (ks << 6) + lkB);
      }
#pragma unroll
      for (int rf = 0; rf < 2; ++rf)
#pragma unroll
        for (int cf = 0; cf < 8; ++cf)
          acc[rf][cf] = mfma16(af[rf], bfr[cf], acc[rf][cf]);
    }
    __syncthreads();   // all waves done reading buf[cur] before it's restaged
  }
#pragma unroll
  for (int cf = 0; cf < 8; ++cf) {
    float bb = bias[n0 + cf * 16 + lrow];
#pragma unroll
    for (int rf = 0; rf < 2; ++rf)
#pragma unroll
      for (int r = 0; r < 4; ++r) {
        int row = m0 + w * 32 + rf * 16 + ((l >> 4) << 2) + r;
        dst[(size_t)row * 4096 + n0 + cf * 16 + lrow] = (bf16_t)(acc[rf][cf][r] + bb);
      }
  }
}

// ---------- k_out2: split-K partial of P@Wcat + vis@Wvcat ----------
// sX holds P||vis as one [64][256] K-tile (rows are 512 B: P at bytes 0..255,
// vis at bytes 256..511). One stage + one gemm per chunk, 2 barriers.
// Weight B-fragments load directly from L2-hot WcatT/WvcatT (no LDS round-trip).
__global__ __launch_bounds__(256, 3) void k_out2(
    const bf16_t* __restrict__ HU, const bf16_t* __restrict__ TU,
    const bf16_t* __restrict__ WcatT, const bf16_t* __restrict__ WvcatT,
    const int* __restrict__ pair_idx, const float* __restrict__ vis,
    float* __restrict__ pacc) {
  __shared__ bf16_t sX[64 * 256];   // 32 KB, swizzled rows of 512 B
  __shared__ int sR0[64], sR1[64];

  const int t = threadIdx.x, w = t >> 6, l = t & 63;
  const int lrow = l & 15, lkB = (l >> 4) << 4;
  const int p0 = blockIdx.x * 64;
  const int ncb = blockIdx.y * 16;

  if (t < 64) { sR0[t] = pair_idx[(p0 + t) * 2]; sR1[t] = pair_idx[(p0 + t) * 2 + 1]; }
  f32x4 acc[4];
#pragma unroll
  for (int cf = 0; cf < 4; ++cf) { f32x4 z = {0.f, 0.f, 0.f, 0.f}; acc[cf] = z; }

  const int srow = t >> 2, sseg = t & 3;
  __syncthreads();
  const bf16_t* hbase = HU + (size_t)sR0[srow] * 4096 + sseg * 32;
  const bf16_t* tbase = TU + (size_t)sR1[srow] * 4096 + sseg * 32;
  const float*  vp    = vis + (size_t)(p0 + srow) * 4096 + sseg * 32;
  // per-lane weight fragment base offset: col*4096 + (l>>4)*8
  const size_t wfo = (size_t)lrow * 4096 + ((l >> 4) << 3);

  bf16x8 hv[4], tv[4]; float4 vv[8];
  {
    const int nb = ncb * 128;
#pragma unroll
    for (int j = 0; j < 4; ++j) {
      hv[j] = *(const bf16x8*)(hbase + nb + j * 8);
      tv[j] = *(const bf16x8*)(tbase + nb + j * 8);
    }
#pragma unroll
    for (int j = 0; j < 8; ++j) vv[j] = *(const float4*)(vp + nb + j * 4);
  }

#pragma unroll 1
  for (int i = 0; i < 16; ++i) {
    const int nb = (ncb + i) * 128;
    // stage P = relu(HU[r0]+TU[r1]) into k 0..127 (bytes 0..255)
#pragma unroll
    for (int j = 0; j < 4; ++j) {
      bf16x8 pv;
#pragma unroll
      for (int e = 0; e < 8; ++e)
        pv[e] = (bf16_t)fmaxf((float)hv[j][e] + (float)tv[j][e], 0.f);
      int cb = (sseg * 32 + j * 8) * 2;
      *(bf16x8*)((char*)sX + (srow << 9) + (cb ^ ((srow & 7) << 4))) = pv;
    }
    // stage vis (f32->bf16) into k 128..255 (bytes 256..511)
#pragma unroll
    for (int j = 0; j < 8; ++j) {
      bf16x4 h4; h4[0] = (bf16_t)vv[j].x; h4[1] = (bf16_t)vv[j].y;
      h4[2] = (bf16_t)vv[j].z; h4[3] = (bf16_t)vv[j].w;
      int cb = 256 + (sseg * 32 + j * 4) * 2;
      *(bf16x4*)((char*)sX + (srow << 9) + (cb ^ ((srow & 7) << 4))) = h4;
    }
    // prefetch next chunk's gathers + vis (land during gemm)
    if (i < 15) {
      const int nb2 = nb + 128;
#pragma unroll
      for (int j = 0; j < 4; ++j) {
        hv[j] = *(const bf16x8*)(hbase + nb2 + j * 8);
        tv[j] = *(const bf16x8*)(tbase + nb2 + j * 8);
      }
#pragma unroll
      for (int j = 0; j < 8; ++j) vv[j] = *(const float4*)(vp + nb2 + j * 4);
    }
    __syncthreads();
    // gemm over K=256 (8 ks): af from LDS, weights direct from global (L2-hot)
    bf16x8 bw[2][4];
#pragma unroll
    for (int cf = 0; cf < 4; ++cf)
      bw[0][cf] = *(const bf16x8*)(WcatT + wfo + (size_t)cf * 65536 + nb);
#pragma unroll
    for (int ks = 0; ks < 8; ++ks) {
      if (ks < 7) {
        const int ksn = ks + 1;
        const bf16_t* Wsel = (ksn < 4) ? WcatT : WvcatT;
        const int ko = nb + (ksn & 3) * 32;
#pragma unroll
        for (int cf = 0; cf < 4; ++cf)
          bw[ksn & 1][cf] = *(const bf16x8*)(Wsel + wfo + (size_t)cf * 65536 + ko);
      }
      int row = w * 16 + lrow;
      bf16x8 af = *(const bf16x8*)((const char*)sX + (row << 9) + (((ks << 6) | lkB) ^ ((row & 7) << 4)));
#pragma unroll
      for (int cf = 0; cf < 4; ++cf)
        acc[cf] = mfma16(af, bw[ks & 1][cf], acc[cf]);
    }
    __syncthreads();
  }

  float* pa = pacc + ((size_t)blockIdx.y * 512 + blockIdx.x) * 64 * 64;
#pragma unroll
  for (int cf = 0; cf < 4; ++cf)
#pragma unroll
    for (int r = 0; r < 4; ++r) {
      int row = w * 16 + ((l >> 4) << 2) + r;
      pa[row * 64 + cf * 16 + lrow] = acc[cf][r];
    }
}

// ---------- k_fin: sum partials + bias + freq epilogue ----------
__global__ __launch_bounds__(256) void k_fin(const float* __restrict__ pacc,
                                             const float* __restrict__ bcv,
                                             const int* __restrict__ pair_pred,
                                             const float* __restrict__ freq,
                                             float* __restrict__ out) {
  int p = blockIdx.x * 256 + threadIdx.x;
  int g = p >> 6, row = p & 63;
  const float* a0 = pacc + ((size_t)g * 64 + row) * 64;
  const float* a1 = pacc + ((size_t)(512 + g) * 64 + row) * 64;
  const float* f = freq + ((size_t)pair_pred[p * 2] * 151 + pair_pred[p * 2 + 1]) * 51;
  float e1 = 0.f, e2 = 0.f, e3 = 0.f;
#pragma unroll
  for (int c = 0; c < 15; ++c) {
    float fb = f[GEO_c[c]]; e1 += expf(fb);
    out[(size_t)p * 15 + c] = a0[c] + a1[c] + bcv[c] + fb;
  }
#pragma unroll
  for (int c = 0; c < 11; ++c) {
    float fb = f[POS_c[c]]; e2 += expf(fb);
    out[491520 + (size_t)p * 11 + c] = a0[15 + c] + a1[15 + c] + bcv[15 + c] + fb;
  }
#pragma unroll
  for (int c = 0; c < 24; ++c) {
    float fb = f[SEM_c[c]]; e3 += expf(fb);
    out[851968 + (size_t)p * 24 + c] = a0[26 + c] + a1[26 + c] + bcv[26 + c] + fb;
  }
  out[1638400 + (size_t)p * 4 + 0] = a0[50] + a1[50] + bcv[50] + f[0];
  out[1638400 + (size_t)p * 4 + 1] = a0[51] + a1[51] + bcv[51] + logf(e1);
  out[1638400 + (size_t)p * 4 + 2] = a0[52] + a1[52] + bcv[52] + logf(e2);
  out[1638400 + (size_t)p * 4 + 3] = a0[53] + a1[53] + bcv[53] + logf(e3);
}

extern "C" void kernel_launch(void* const* d_in, const int* in_sizes, int n_in,
                              void* d_out, int out_size, void* d_ws, size_t ws_size,
                              hipStream_t stream) {
  const float* edge_ctx  = (const float*)d_in[0];
  const int*   pair_idx  = (const int*)d_in[1];
  const float* vis_rep   = (const float*)d_in[2];
  const int*   pair_pred = (const int*)d_in[3];
  const float* Wpe = (const float*)d_in[4];
  const float* bpe = (const float*)d_in[5];
  const float* Wpc = (const float*)d_in[6];
  const float* bpc = (const float*)d_in[7];
  const float* Wc1 = (const float*)d_in[8];  const float* bc1 = (const float*)d_in[9];
  const float* Wc2 = (const float*)d_in[10]; const float* bc2 = (const float*)d_in[11];
  const float* Wc3 = (const float*)d_in[12]; const float* bc3 = (const float*)d_in[13];
  const float* Wcs = (const float*)d_in[14]; const float* bcs = (const float*)d_in[15];
  const float* Wv1 = (const float*)d_in[16]; const float* bv1 = (const float*)d_in[17];
  const float* Wv2 = (const float*)d_in[18]; const float* bv2 = (const float*)d_in[19];
  const float* Wv3 = (const float*)d_in[20]; const float* bv3 = (const float*)d_in[21];
  const float* Wvs = (const float*)d_in[22]; const float* bvs = (const float*)d_in[23];
  const float* freq = (const float*)d_in[24];
  float* out = (float*)d_out;

  char* ws = (char*)d_ws;
  bf16_t* WpcT   = (bf16_t*)(ws + 0);           //  8388608
  bf16_t* W1T    = (bf16_t*)(ws + 8388608);     //  4194304
  bf16_t* W2T    = (bf16_t*)(ws + 12582912);    //  4194304
  float*  pacc   = (float*)(ws + 0);            // 16777216 (alias; W* dead by k_out2)
  bf16_t* ecb    = (bf16_t*)(ws + 16777216);    //  8388608
  bf16_t* WcatT  = (bf16_t*)(ws + 25165824);    //   524288
  bf16_t* WvcatT = (bf16_t*)(ws + 25690112);    //   524288
  float*  bcv    = (float*)(ws + 26214400);     //     4096 (pad)
  float*  b12    = (float*)(ws + 26218496);     //    32768
  bf16_t* HU     = (bf16_t*)(ws + 26251264);    // 67108864
  bf16_t* TU     = (bf16_t*)(ws + 93360128);    // 67108864  -> end 160468992

  k_transpose<<<dim3(64, 16), 256, 0, stream>>>(Wpc, WpcT, 1024, 4096);
  k_pack_cat<<<64, 256, 0, stream>>>(Wc1, Wc2, Wc3, Wcs, Wv1, Wv2, Wv3, Wvs,
                                     bc1, bc2, bc3, bcs, bv1, bv2, bv3, bvs,
                                     WcatT, WvcatT, bcv);
  k_ec<<<2048, 256, 0, stream>>>(edge_ctx, ecb);
  k_w12<<<dim3(4, 32, 2), 256, 0, stream>>>(WpcT, Wpe, W1T, W2T);
  k_bias<<<1024, 256, 0, stream>>>(WpcT, bpe, bpc, b12);
  k_ht2<<<dim3(32, 64, 2), 256, 0, stream>>>(ecb, W1T, W2T, b12, HU, TU);
  k_out2<<<dim3(512, 2), 256, 0, stream>>>(HU, TU, WcatT, WvcatT, pair_idx, vis_rep, pacc);
  k_fin<<<128, 256, 0, stream>>>(pacc, bcv, pair_pred, freq, out);
}

// Round 6
// 568.751 us; speedup vs baseline: 1.0010x; 1.0010x over previous
//
#include <hip/hip_runtime.h>
#include <hip/hip_bf16.h>

typedef __bf16 bf16_t;
typedef __bf16 bf16x8 __attribute__((ext_vector_type(8)));
typedef __bf16 bf16x4 __attribute__((ext_vector_type(4)));
typedef float f32x4 __attribute__((ext_vector_type(4)));

#define DI __device__ __forceinline__

DI f32x4 mfma16(bf16x8 a, bf16x8 b, f32x4 c) {
  return __builtin_amdgcn_mfma_f32_16x16x32_bf16(a, b, c, 0, 0, 0);
}

DI void gload16(const bf16_t* g, bf16_t* l) {
  __builtin_amdgcn_global_load_lds(
      (const __attribute__((address_space(1))) unsigned int*)g,
      (__attribute__((address_space(3))) unsigned int*)l, 16, 0, 0);
}

__constant__ int GEO_c[15] = {1,2,3,4,5,6,8,10,22,23,29,31,32,33,43};
__constant__ int POS_c[11] = {9,16,17,20,27,30,36,42,48,49,50};
__constant__ int SEM_c[24] = {7,11,12,13,14,15,18,19,21,24,25,26,28,34,35,37,38,39,40,41,44,45,46,47};

// ---------- prep: transpose f32 Wpc [1024][4096] -> bf16 WpcT [4096][1024] ----------
__global__ void k_transpose(const float* __restrict__ src, bf16_t* __restrict__ dst,
                            int K, int N) {
  __shared__ float s[64][65];
  int n0 = blockIdx.x * 64, k0 = blockIdx.y * 64;
  int t = threadIdx.x;
#pragma unroll
  for (int i = 0; i < 4; ++i) {
    int idx = t + i * 256; int kr = idx >> 4, seg = idx & 15;
    float4 v = *(const float4*)(src + (size_t)(k0 + kr) * N + n0 + seg * 4);
    s[kr][seg * 4 + 0] = v.x; s[kr][seg * 4 + 1] = v.y;
    s[kr][seg * 4 + 2] = v.z; s[kr][seg * 4 + 3] = v.w;
  }
  __syncthreads();
#pragma unroll
  for (int i = 0; i < 4; ++i) {
    int idx = t + i * 256; int nr = idx >> 4, seg = idx & 15;
    bf16x4 h;
    h[0] = (bf16_t)s[seg * 4 + 0][nr]; h[1] = (bf16_t)s[seg * 4 + 1][nr];
    h[2] = (bf16_t)s[seg * 4 + 2][nr]; h[3] = (bf16_t)s[seg * 4 + 3][nr];
    *(bf16x4*)(dst + (size_t)(n0 + nr) * K + k0 + seg * 4) = h;
  }
}

// ---------- prep: pack Wc*/Wv* into [64][4096] bf16 (cols 54..63 zero), bcv ----------
DI void cat_map(int j, int& which, int& sub, int& nc) {
  if (j < 15)      { which = 0; sub = j;      nc = 15; }
  else if (j < 26) { which = 1; sub = j - 15; nc = 11; }
  else if (j < 50) { which = 2; sub = j - 26; nc = 24; }
  else if (j < 54) { which = 3; sub = j - 50; nc = 4;  }
  else             { which = 4; sub = 0;      nc = 1;  }
}

__global__ void k_pack_cat(const float* __restrict__ Wc1, const float* __restrict__ Wc2,
                           const float* __restrict__ Wc3, const float* __restrict__ Wcs,
                           const float* __restrict__ Wv1, const float* __restrict__ Wv2,
                           const float* __restrict__ Wv3, const float* __restrict__ Wvs,
                           const float* __restrict__ bc1, const float* __restrict__ bc2,
                           const float* __restrict__ bc3, const float* __restrict__ bcs,
                           const float* __restrict__ bv1, const float* __restrict__ bv2,
                           const float* __restrict__ bv3, const float* __restrict__ bvs,
                           bf16_t* __restrict__ WcatT, bf16_t* __restrict__ WvcatT,
                           float* __restrict__ bcv) {
  int j = blockIdx.x, t = threadIdx.x;
  int which, sub, nc; cat_map(j, which, sub, nc);
  const float* Wc = which == 0 ? Wc1 : which == 1 ? Wc2 : which == 2 ? Wc3 : Wcs;
  const float* Wv = which == 0 ? Wv1 : which == 1 ? Wv2 : which == 2 ? Wv3 : Wvs;
  for (int i = 0; i < 16; ++i) {
    int k = t + i * 256;
    float vc = 0.f, vv = 0.f;
    if (which < 4) { vc = Wc[(size_t)k * nc + sub]; vv = Wv[(size_t)k * nc + sub]; }
    WcatT[(size_t)j * 4096 + k] = (bf16_t)vc;
    WvcatT[(size_t)j * 4096 + k] = (bf16_t)vv;
  }
  if (t == 0) {
    float b = 0.f;
    if (which < 4) {
      const float* bc = which == 0 ? bc1 : which == 1 ? bc2 : which == 2 ? bc3 : bcs;
      const float* bv = which == 0 ? bv1 : which == 1 ? bv2 : which == 2 ? bv3 : bvs;
      b = bc[sub] + bv[sub];
    }
    bcv[j] = b;
  }
}

// ---------- prep: ec f32 -> ecb bf16 ----------
__global__ __launch_bounds__(256) void k_ec(const float* __restrict__ ec,
                                            bf16_t* __restrict__ ecb) {
  size_t i = ((size_t)blockIdx.x * 256 + threadIdx.x) * 8;
  float4 a = *(const float4*)(ec + i), b = *(const float4*)(ec + i + 4);
  bf16x8 h;
  h[0] = (bf16_t)a.x; h[1] = (bf16_t)a.y; h[2] = (bf16_t)a.z; h[3] = (bf16_t)a.w;
  h[4] = (bf16_t)b.x; h[5] = (bf16_t)b.y; h[6] = (bf16_t)b.z; h[7] = (bf16_t)b.w;
  *(bf16x8*)(ecb + i) = h;
}

// ---------- prep: W1T[n][k] = sum_j WpcT[n, joff+j] * Wpe[k, joff+j] ----------
__global__ __launch_bounds__(256) void k_w12(const bf16_t* __restrict__ WpcT,
                                             const float* __restrict__ Wpe,
                                             bf16_t* __restrict__ W1T,
                                             bf16_t* __restrict__ W2T) {
  __shared__ bf16_t sA[128 * 64];
  __shared__ bf16_t sB[128 * 64];
  const int t = threadIdx.x, w = t >> 6, l = t & 63;
  const int lrow = l & 15, lkB = (l >> 4) << 4;
  const int k0 = blockIdx.x * 128, n0 = blockIdx.y * 128;
  const int joff = blockIdx.z * 512;
  bf16_t* dst = blockIdx.z ? W2T : W1T;

  f32x4 acc[2][8];
#pragma unroll
  for (int rf = 0; rf < 2; ++rf)
#pragma unroll
    for (int cf = 0; cf < 8; ++cf) { f32x4 z = {0.f, 0.f, 0.f, 0.f}; acc[rf][cf] = z; }

  for (int jj = 0; jj < 512; jj += 64) {
    __syncthreads();
#pragma unroll
    for (int i = 0; i < 4; ++i) {
      int row = (t >> 3) + (i << 5), seg = t & 7;
      bf16x8 v = *(const bf16x8*)(WpcT + (size_t)(n0 + row) * 1024 + joff + jj + seg * 8);
      *(bf16x8*)((char*)sA + (row << 7) + ((seg << 4) ^ ((row & 7) << 4))) = v;
    }
#pragma unroll
    for (int i = 0; i < 8; ++i) {
      int idx = t + i * 256; int row = idx >> 4, seg = idx & 15;
      float4 v = *(const float4*)(Wpe + (size_t)(k0 + row) * 1024 + joff + jj + seg * 4);
      bf16x4 h; h[0] = (bf16_t)v.x; h[1] = (bf16_t)v.y; h[2] = (bf16_t)v.z; h[3] = (bf16_t)v.w;
      *(bf16x4*)((char*)sB + (row << 7) + ((seg << 3) ^ ((row & 7) << 4))) = h;
    }
    __syncthreads();
#pragma unroll
    for (int ks = 0; ks < 2; ++ks) {
      bf16x8 af[2], bfr[8];
#pragma unroll
      for (int rf = 0; rf < 2; ++rf) {
        int row = w * 32 + rf * 16 + lrow;
        af[rf] = *(const bf16x8*)((const char*)sA + (row << 7) + (((ks << 6) | lkB) ^ ((row & 7) << 4)));
      }
#pragma unroll
      for (int cf = 0; cf < 8; ++cf) {
        int col = cf * 16 + lrow;
        bfr[cf] = *(const bf16x8*)((const char*)sB + (col << 7) + (((ks << 6) | lkB) ^ ((col & 7) << 4)));
      }
#pragma unroll
      for (int rf = 0; rf < 2; ++rf)
#pragma unroll
        for (int cf = 0; cf < 8; ++cf)
          acc[rf][cf] = mfma16(af[rf], bfr[cf], acc[rf][cf]);
    }
  }
#pragma unroll
  for (int cf = 0; cf < 8; ++cf)
#pragma unroll
    for (int rf = 0; rf < 2; ++rf)
#pragma unroll
      for (int r = 0; r < 4; ++r) {
        int nrow = n0 + w * 32 + rf * 16 + ((l >> 4) << 2) + r;
        dst[(size_t)nrow * 512 + k0 + cf * 16 + lrow] = (bf16_t)acc[rf][cf][r];
      }
}

// ---------- prep: b12[0][n] = bpe_h . WpcT[n,:512] + bpc[n]; b12[1][n] = bpe_t . WpcT[n,512:] ----------
__global__ __launch_bounds__(256) void k_bias(const bf16_t* __restrict__ WpcT,
                                              const float* __restrict__ bpe,
                                              const float* __restrict__ bpc,
                                              float* __restrict__ b12) {
  int w = threadIdx.x >> 6, l = threadIdx.x & 63;
  int n = blockIdx.x * 4 + w;
  const bf16_t* r = WpcT + (size_t)n * 1024;
  bf16x8 v1 = *(const bf16x8*)(r + l * 8);
  bf16x8 v2 = *(const bf16x8*)(r + 512 + l * 8);
  float s1 = 0.f, s2 = 0.f;
#pragma unroll
  for (int e = 0; e < 8; ++e) {
    s1 += (float)v1[e] * bpe[l * 8 + e];
    s2 += (float)v2[e] * bpe[512 + l * 8 + e];
  }
#pragma unroll
  for (int off = 32; off; off >>= 1) {
    s1 += __shfl_down(s1, off);
    s2 += __shfl_down(s2, off);
  }
  if (l == 0) { b12[n] = s1 + bpc[n]; b12[4096 + n] = s2; }
}

// ---------- k_ht2: HU/TU = ecb @ W{1,2}T + b12 (2-phase dbuf, counted vmcnt) ----------
__global__ __launch_bounds__(256, 2) void k_ht2(const bf16_t* __restrict__ ecb,
                                                const bf16_t* __restrict__ W1T,
                                                const bf16_t* __restrict__ W2T,
                                                const float* __restrict__ b12,
                                                bf16_t* __restrict__ HU,
                                                bf16_t* __restrict__ TU) {
  __shared__ bf16_t sA[2][128 * 64];
  __shared__ bf16_t sB[2][128 * 64];
  const int t = threadIdx.x, w = t >> 6, l = t & 63;
  const int lrow = l & 15, lkB = (l >> 4) << 4;
  const int n0 = blockIdx.x * 128, m0 = blockIdx.y * 128, z = blockIdx.z;
  const bf16_t* Bw = z ? W2T : W1T;
  const float* bias = b12 + z * 4096;
  bf16_t* dst = z ? TU : HU;

  const int srow = (w << 5) + (l >> 3);
  const int sk = (l & 7) * 8;
  const bf16_t* gA = ecb + (size_t)(m0 + srow) * 512 + sk;
  const bf16_t* gB = Bw + (size_t)(n0 + srow) * 512 + sk;
  const int lofs = (w << 11);

  f32x4 acc[2][8];
#pragma unroll
  for (int rf = 0; rf < 2; ++rf)
#pragma unroll
    for (int cf = 0; cf < 8; ++cf) { f32x4 zz = {0.f, 0.f, 0.f, 0.f}; acc[rf][cf] = zz; }

#pragma unroll
  for (int i = 0; i < 4; ++i) gload16(gA + i * 4096, &sA[0][lofs] + i * 512);
#pragma unroll
  for (int i = 0; i < 4; ++i) gload16(gB + i * 4096, &sB[0][lofs] + i * 512);

#pragma unroll 1
  for (int tt = 0; tt < 8; ++tt) {
    const int cur = tt & 1;
    if (tt < 7) {
      const int kk = (tt + 1) * 64;
#pragma unroll
      for (int i = 0; i < 4; ++i) gload16(gA + i * 4096 + kk, &sA[cur ^ 1][lofs] + i * 512);
#pragma unroll
      for (int i = 0; i < 4; ++i) gload16(gB + i * 4096 + kk, &sB[cur ^ 1][lofs] + i * 512);
      asm volatile("s_waitcnt vmcnt(8)" ::: "memory");
    } else {
      asm volatile("s_waitcnt vmcnt(0)" ::: "memory");
    }
    __syncthreads();
#pragma unroll
    for (int ks = 0; ks < 2; ++ks) {
      bf16x8 af[2], bfr[8];
#pragma unroll
      for (int rf = 0; rf < 2; ++rf) {
        int row = w * 32 + rf * 16 + lrow;
        af[rf] = *(const bf16x8*)((const char*)&sA[cur][0] + (row << 7) + (ks << 6) + lkB);
      }
#pragma unroll
      for (int cf = 0; cf < 8; ++cf) {
        int col = cf * 16 + lrow;
        bfr[cf] = *(const bf16x8*)((const char*)&sB[cur][0] + (col << 7) + (ks << 6) + lkB);
      }
#pragma unroll
      for (int rf = 0; rf < 2; ++rf)
#pragma unroll
        for (int cf = 0; cf < 8; ++cf)
          acc[rf][cf] = mfma16(af[rf], bfr[cf], acc[rf][cf]);
    }
    __syncthreads();
  }
#pragma unroll
  for (int cf = 0; cf < 8; ++cf) {
    float bb = bias[n0 + cf * 16 + lrow];
#pragma unroll
    for (int rf = 0; rf < 2; ++rf)
#pragma unroll
      for (int r = 0; r < 4; ++r) {
        int row = m0 + w * 32 + rf * 16 + ((l >> 4) << 2) + r;
        dst[(size_t)row * 4096 + n0 + cf * 16 + lrow] = (bf16_t)(acc[rf][cf][r] + bb);
      }
  }
}

// ---------- k_out3: all-register split-K partial of P@Wcat + vis@Wvcat ----------
// No LDS, no barriers. Each wave owns 16 pairs; lane l builds the MFMA A-fragment
// for pair row (l&15) at k-segment (l>>4)*8 via direct gathers; weights are
// fragment-loaded from L2-hot WcatT/WvcatT. Compiler free to pipeline 48
// independent loads per chunk across MFMAs.
__global__ __launch_bounds__(256, 3) void k_out3(
    const bf16_t* __restrict__ HU, const bf16_t* __restrict__ TU,
    const bf16_t* __restrict__ WcatT, const bf16_t* __restrict__ WvcatT,
    const int* __restrict__ pair_idx, const float* __restrict__ vis,
    float* __restrict__ pacc) {
  const int t = threadIdx.x, w = t >> 6, l = t & 63;
  const int lrow = l & 15, lseg = l >> 4;
  const int p0 = blockIdx.x * 64;
  const int myp = p0 + w * 16 + lrow;   // pair this lane feeds into the A-fragment

  const int r0 = pair_idx[myp * 2];
  const int r1 = pair_idx[myp * 2 + 1];

  const bf16_t* hb  = HU + (size_t)r0 * 4096 + lseg * 8;
  const bf16_t* tb  = TU + (size_t)r1 * 4096 + lseg * 8;
  const float*  vb  = vis + (size_t)myp * 4096 + lseg * 8;
  const bf16_t* wcb = WcatT + (size_t)lrow * 4096 + lseg * 8;
  const bf16_t* wvb = WvcatT + (size_t)lrow * 4096 + lseg * 8;

  f32x4 acc[4];
#pragma unroll
  for (int cf = 0; cf < 4; ++cf) { f32x4 z = {0.f, 0.f, 0.f, 0.f}; acc[cf] = z; }

#pragma unroll 1
  for (int c = 0; c < 8; ++c) {
    const int nb = ((int)blockIdx.y * 8 + c) * 128;
    // P half: ks 0..3 (k = nb .. nb+127)
#pragma unroll
    for (int ks = 0; ks < 4; ++ks) {
      const int ko = nb + ks * 32;
      bf16x8 hv = *(const bf16x8*)(hb + ko);
      bf16x8 tv = *(const bf16x8*)(tb + ko);
      bf16x8 af;
#pragma unroll
      for (int e = 0; e < 8; ++e)
        af[e] = (bf16_t)fmaxf((float)hv[e] + (float)tv[e], 0.f);
#pragma unroll
      for (int cf = 0; cf < 4; ++cf) {
        bf16x8 bw = *(const bf16x8*)(wcb + (size_t)cf * 65536 + ko);
        acc[cf] = mfma16(af, bw, acc[cf]);
      }
    }
    // vis half: ks 0..3 over the same k range, vs Wvcat
#pragma unroll
    for (int ks = 0; ks < 4; ++ks) {
      const int ko = nb + ks * 32;
      float4 v0 = *(const float4*)(vb + ko);
      float4 v1 = *(const float4*)(vb + ko + 4);
      bf16x8 af;
      af[0] = (bf16_t)v0.x; af[1] = (bf16_t)v0.y; af[2] = (bf16_t)v0.z; af[3] = (bf16_t)v0.w;
      af[4] = (bf16_t)v1.x; af[5] = (bf16_t)v1.y; af[6] = (bf16_t)v1.z; af[7] = (bf16_t)v1.w;
#pragma unroll
      for (int cf = 0; cf < 4; ++cf) {
        bf16x8 bw = *(const bf16x8*)(wvb + (size_t)cf * 65536 + ko);
        acc[cf] = mfma16(af, bw, acc[cf]);
      }
    }
  }

  float* pa = pacc + ((size_t)blockIdx.y * 512 + blockIdx.x) * 64 * 64;
#pragma unroll
  for (int cf = 0; cf < 4; ++cf)
#pragma unroll
    for (int r = 0; r < 4; ++r) {
      int row = w * 16 + (l >> 4) * 4 + r;   // D layout: col=lane&15, row=(lane>>4)*4+r
      pa[row * 64 + cf * 16 + lrow] = acc[cf][r];
    }
}

// ---------- k_fin: sum 4 partials + bias + freq epilogue ----------
__global__ __launch_bounds__(256) void k_fin(const float* __restrict__ pacc,
                                             const float* __restrict__ bcv,
                                             const int* __restrict__ pair_pred,
                                             const float* __restrict__ freq,
                                             float* __restrict__ out) {
  int p = blockIdx.x * 256 + threadIdx.x;
  int g = p >> 6, row = p & 63;
  const float* a0 = pacc + (((size_t)0 * 512 + g) * 64 + row) * 64;
  const float* a1 = pacc + (((size_t)1 * 512 + g) * 64 + row) * 64;
  const float* a2 = pacc + (((size_t)2 * 512 + g) * 64 + row) * 64;
  const float* a3 = pacc + (((size_t)3 * 512 + g) * 64 + row) * 64;
  const float* f = freq + ((size_t)pair_pred[p * 2] * 151 + pair_pred[p * 2 + 1]) * 51;
  float e1 = 0.f, e2 = 0.f, e3 = 0.f;
#pragma unroll
  for (int c = 0; c < 15; ++c) {
    float fb = f[GEO_c[c]]; e1 += expf(fb);
    out[(size_t)p * 15 + c] = a0[c] + a1[c] + a2[c] + a3[c] + bcv[c] + fb;
  }
#pragma unroll
  for (int c = 0; c < 11; ++c) {
    float fb = f[POS_c[c]]; e2 += expf(fb);
    out[491520 + (size_t)p * 11 + c] = a0[15 + c] + a1[15 + c] + a2[15 + c] + a3[15 + c] + bcv[15 + c] + fb;
  }
#pragma unroll
  for (int c = 0; c < 24; ++c) {
    float fb = f[SEM_c[c]]; e3 += expf(fb);
    out[851968 + (size_t)p * 24 + c] = a0[26 + c] + a1[26 + c] + a2[26 + c] + a3[26 + c] + bcv[26 + c] + fb;
  }
  out[1638400 + (size_t)p * 4 + 0] = a0[50] + a1[50] + a2[50] + a3[50] + bcv[50] + f[0];
  out[1638400 + (size_t)p * 4 + 1] = a0[51] + a1[51] + a2[51] + a3[51] + bcv[51] + logf(e1);
  out[1638400 + (size_t)p * 4 + 2] = a0[52] + a1[52] + a2[52] + a3[52] + bcv[52] + logf(e2);
  out[1638400 + (size_t)p * 4 + 3] = a0[53] + a1[53] + a2[53] + a3[53] + bcv[53] + logf(e3);
}

extern "C" void kernel_launch(void* const* d_in, const int* in_sizes, int n_in,
                              void* d_out, int out_size, void* d_ws, size_t ws_size,
                              hipStream_t stream) {
  const float* edge_ctx  = (const float*)d_in[0];
  const int*   pair_idx  = (const int*)d_in[1];
  const float* vis_rep   = (const float*)d_in[2];
  const int*   pair_pred = (const int*)d_in[3];
  const float* Wpe = (const float*)d_in[4];
  const float* bpe = (const float*)d_in[5];
  const float* Wpc = (const float*)d_in[6];
  const float* bpc = (const float*)d_in[7];
  const float* Wc1 = (const float*)d_in[8];  const float* bc1 = (const float*)d_in[9];
  const float* Wc2 = (const float*)d_in[10]; const float* bc2 = (const float*)d_in[11];
  const float* Wc3 = (const float*)d_in[12]; const float* bc3 = (const float*)d_in[13];
  const float* Wcs = (const float*)d_in[14]; const float* bcs = (const float*)d_in[15];
  const float* Wv1 = (const float*)d_in[16]; const float* bv1 = (const float*)d_in[17];
  const float* Wv2 = (const float*)d_in[18]; const float* bv2 = (const float*)d_in[19];
  const float* Wv3 = (const float*)d_in[20]; const float* bv3 = (const float*)d_in[21];
  const float* Wvs = (const float*)d_in[22]; const float* bvs = (const float*)d_in[23];
  const float* freq = (const float*)d_in[24];
  float* out = (float*)d_out;

  char* ws = (char*)d_ws;
  // region [0, 33.6 MB): prep buffers, all dead before k_out3; pacc aliases it.
  bf16_t* WpcT   = (bf16_t*)(ws + 0);           //  8388608
  bf16_t* W1T    = (bf16_t*)(ws + 8388608);     //  4194304
  bf16_t* W2T    = (bf16_t*)(ws + 12582912);    //  4194304
  bf16_t* ecb    = (bf16_t*)(ws + 16777216);    //  8388608
  float*  pacc   = (float*)(ws + 0);            // 33554432 (alias)
  bf16_t* WcatT  = (bf16_t*)(ws + 33554432);    //   524288
  bf16_t* WvcatT = (bf16_t*)(ws + 34078720);    //   524288
  float*  bcv    = (float*)(ws + 34603008);     //     4096 (pad)
  float*  b12    = (float*)(ws + 34607104);     //    32768
  bf16_t* HU     = (bf16_t*)(ws + 34639872);    // 67108864
  bf16_t* TU     = (bf16_t*)(ws + 101748736);   // 67108864  -> end 168857600

  k_transpose<<<dim3(64, 16), 256, 0, stream>>>(Wpc, WpcT, 1024, 4096);
  k_pack_cat<<<64, 256, 0, stream>>>(Wc1, Wc2, Wc3, Wcs, Wv1, Wv2, Wv3, Wvs,
                                     bc1, bc2, bc3, bcs, bv1, bv2, bv3, bvs,
                                     WcatT, WvcatT, bcv);
  k_ec<<<2048, 256, 0, stream>>>(edge_ctx, ecb);
  k_w12<<<dim3(4, 32, 2), 256, 0, stream>>>(WpcT, Wpe, W1T, W2T);
  k_bias<<<1024, 256, 0, stream>>>(WpcT, bpe, bpc, b12);
  k_ht2<<<dim3(32, 64, 2), 256, 0, stream>>>(ecb, W1T, W2T, b12, HU, TU);
  k_out3<<<dim3(512, 4), 256, 0, stream>>>(HU, TU, WcatT, WvcatT, pair_idx, vis_rep, pacc);
  k_fin<<<128, 256, 0, stream>>>(pacc, bcv, pair_pred, freq, out);
}

// Round 7
// 496.965 us; speedup vs baseline: 1.1456x; 1.1445x over previous
//
#include <hip/hip_runtime.h>
#include <hip/hip_bf16.h>

typedef __bf16 bf16_t;
typedef __bf16 bf16x8 __attribute__((ext_vector_type(8)));
typedef __bf16 bf16x4 __attribute__((ext_vector_type(4)));
typedef float f32x4 __attribute__((ext_vector_type(4)));

#define DI __device__ __forceinline__

DI f32x4 mfma16(bf16x8 a, bf16x8 b, f32x4 c) {
  return __builtin_amdgcn_mfma_f32_16x16x32_bf16(a, b, c, 0, 0, 0);
}

DI void gload16(const void* g, void* l) {
  __builtin_amdgcn_global_load_lds(
      (const __attribute__((address_space(1))) unsigned int*)g,
      (__attribute__((address_space(3))) unsigned int*)l, 16, 0, 0);
}

__constant__ int GEO_c[15] = {1,2,3,4,5,6,8,10,22,23,29,31,32,33,43};
__constant__ int POS_c[11] = {9,16,17,20,27,30,36,42,48,49,50};
__constant__ int SEM_c[24] = {7,11,12,13,14,15,18,19,21,24,25,26,28,34,35,37,38,39,40,41,44,45,46,47};

// ---------- prep: transpose f32 Wpc [1024][4096] -> bf16 WpcT [4096][1024] ----------
__global__ void k_transpose(const float* __restrict__ src, bf16_t* __restrict__ dst,
                            int K, int N) {
  __shared__ float s[64][65];
  int n0 = blockIdx.x * 64, k0 = blockIdx.y * 64;
  int t = threadIdx.x;
#pragma unroll
  for (int i = 0; i < 4; ++i) {
    int idx = t + i * 256; int kr = idx >> 4, seg = idx & 15;
    float4 v = *(const float4*)(src + (size_t)(k0 + kr) * N + n0 + seg * 4);
    s[kr][seg * 4 + 0] = v.x; s[kr][seg * 4 + 1] = v.y;
    s[kr][seg * 4 + 2] = v.z; s[kr][seg * 4 + 3] = v.w;
  }
  __syncthreads();
#pragma unroll
  for (int i = 0; i < 4; ++i) {
    int idx = t + i * 256; int nr = idx >> 4, seg = idx & 15;
    bf16x4 h;
    h[0] = (bf16_t)s[seg * 4 + 0][nr]; h[1] = (bf16_t)s[seg * 4 + 1][nr];
    h[2] = (bf16_t)s[seg * 4 + 2][nr]; h[3] = (bf16_t)s[seg * 4 + 3][nr];
    *(bf16x4*)(dst + (size_t)(n0 + nr) * K + k0 + seg * 4) = h;
  }
}

// ---------- prep: pack Wc*/Wv* into [64][4096] bf16 (cols 54..63 zero), bcv ----------
DI void cat_map(int j, int& which, int& sub, int& nc) {
  if (j < 15)      { which = 0; sub = j;      nc = 15; }
  else if (j < 26) { which = 1; sub = j - 15; nc = 11; }
  else if (j < 50) { which = 2; sub = j - 26; nc = 24; }
  else if (j < 54) { which = 3; sub = j - 50; nc = 4;  }
  else             { which = 4; sub = 0;      nc = 1;  }
}

__global__ void k_pack_cat(const float* __restrict__ Wc1, const float* __restrict__ Wc2,
                           const float* __restrict__ Wc3, const float* __restrict__ Wcs,
                           const float* __restrict__ Wv1, const float* __restrict__ Wv2,
                           const float* __restrict__ Wv3, const float* __restrict__ Wvs,
                           const float* __restrict__ bc1, const float* __restrict__ bc2,
                           const float* __restrict__ bc3, const float* __restrict__ bcs,
                           const float* __restrict__ bv1, const float* __restrict__ bv2,
                           const float* __restrict__ bv3, const float* __restrict__ bvs,
                           bf16_t* __restrict__ WcatT, bf16_t* __restrict__ WvcatT,
                           float* __restrict__ bcv) {
  int j = blockIdx.x, t = threadIdx.x;
  int which, sub, nc; cat_map(j, which, sub, nc);
  const float* Wc = which == 0 ? Wc1 : which == 1 ? Wc2 : which == 2 ? Wc3 : Wcs;
  const float* Wv = which == 0 ? Wv1 : which == 1 ? Wv2 : which == 2 ? Wv3 : Wvs;
  for (int i = 0; i < 16; ++i) {
    int k = t + i * 256;
    float vc = 0.f, vv = 0.f;
    if (which < 4) { vc = Wc[(size_t)k * nc + sub]; vv = Wv[(size_t)k * nc + sub]; }
    WcatT[(size_t)j * 4096 + k] = (bf16_t)vc;
    WvcatT[(size_t)j * 4096 + k] = (bf16_t)vv;
  }
  if (t == 0) {
    float b = 0.f;
    if (which < 4) {
      const float* bc = which == 0 ? bc1 : which == 1 ? bc2 : which == 2 ? bc3 : bcs;
      const float* bv = which == 0 ? bv1 : which == 1 ? bv2 : which == 2 ? bv3 : bvs;
      b = bc[sub] + bv[sub];
    }
    bcv[j] = b;
  }
}

// ---------- prep: ec f32 -> ecb bf16 ----------
__global__ __launch_bounds__(256) void k_ec(const float* __restrict__ ec,
                                            bf16_t* __restrict__ ecb) {
  size_t i = ((size_t)blockIdx.x * 256 + threadIdx.x) * 8;
  float4 a = *(const float4*)(ec + i), b = *(const float4*)(ec + i + 4);
  bf16x8 h;
  h[0] = (bf16_t)a.x; h[1] = (bf16_t)a.y; h[2] = (bf16_t)a.z; h[3] = (bf16_t)a.w;
  h[4] = (bf16_t)b.x; h[5] = (bf16_t)b.y; h[6] = (bf16_t)b.z; h[7] = (bf16_t)b.w;
  *(bf16x8*)(ecb + i) = h;
}

// ---------- prep: W1T[n][k] = sum_j WpcT[n, joff+j] * Wpe[k, joff+j] ----------
__global__ __launch_bounds__(256) void k_w12(const bf16_t* __restrict__ WpcT,
                                             const float* __restrict__ Wpe,
                                             bf16_t* __restrict__ W1T,
                                             bf16_t* __restrict__ W2T) {
  __shared__ bf16_t sA[128 * 64];
  __shared__ bf16_t sB[128 * 64];
  const int t = threadIdx.x, w = t >> 6, l = t & 63;
  const int lrow = l & 15, lkB = (l >> 4) << 4;
  const int k0 = blockIdx.x * 128, n0 = blockIdx.y * 128;
  const int joff = blockIdx.z * 512;
  bf16_t* dst = blockIdx.z ? W2T : W1T;

  f32x4 acc[2][8];
#pragma unroll
  for (int rf = 0; rf < 2; ++rf)
#pragma unroll
    for (int cf = 0; cf < 8; ++cf) { f32x4 z = {0.f, 0.f, 0.f, 0.f}; acc[rf][cf] = z; }

  for (int jj = 0; jj < 512; jj += 64) {
    __syncthreads();
#pragma unroll
    for (int i = 0; i < 4; ++i) {
      int row = (t >> 3) + (i << 5), seg = t & 7;
      bf16x8 v = *(const bf16x8*)(WpcT + (size_t)(n0 + row) * 1024 + joff + jj + seg * 8);
      *(bf16x8*)((char*)sA + (row << 7) + ((seg << 4) ^ ((row & 7) << 4))) = v;
    }
#pragma unroll
    for (int i = 0; i < 8; ++i) {
      int idx = t + i * 256; int row = idx >> 4, seg = idx & 15;
      float4 v = *(const float4*)(Wpe + (size_t)(k0 + row) * 1024 + joff + jj + seg * 4);
      bf16x4 h; h[0] = (bf16_t)v.x; h[1] = (bf16_t)v.y; h[2] = (bf16_t)v.z; h[3] = (bf16_t)v.w;
      *(bf16x4*)((char*)sB + (row << 7) + ((seg << 3) ^ ((row & 7) << 4))) = h;
    }
    __syncthreads();
#pragma unroll
    for (int ks = 0; ks < 2; ++ks) {
      bf16x8 af[2], bfr[8];
#pragma unroll
      for (int rf = 0; rf < 2; ++rf) {
        int row = w * 32 + rf * 16 + lrow;
        af[rf] = *(const bf16x8*)((const char*)sA + (row << 7) + (((ks << 6) | lkB) ^ ((row & 7) << 4)));
      }
#pragma unroll
      for (int cf = 0; cf < 8; ++cf) {
        int col = cf * 16 + lrow;
        bfr[cf] = *(const bf16x8*)((const char*)sB + (col << 7) + (((ks << 6) | lkB) ^ ((col & 7) << 4)));
      }
#pragma unroll
      for (int rf = 0; rf < 2; ++rf)
#pragma unroll
        for (int cf = 0; cf < 8; ++cf)
          acc[rf][cf] = mfma16(af[rf], bfr[cf], acc[rf][cf]);
    }
  }
#pragma unroll
  for (int cf = 0; cf < 8; ++cf)
#pragma unroll
    for (int rf = 0; rf < 2; ++rf)
#pragma unroll
      for (int r = 0; r < 4; ++r) {
        int nrow = n0 + w * 32 + rf * 16 + ((l >> 4) << 2) + r;
        dst[(size_t)nrow * 512 + k0 + cf * 16 + lrow] = (bf16_t)acc[rf][cf][r];
      }
}

// ---------- prep: b12 ----------
__global__ __launch_bounds__(256) void k_bias(const bf16_t* __restrict__ WpcT,
                                              const float* __restrict__ bpe,
                                              const float* __restrict__ bpc,
                                              float* __restrict__ b12) {
  int w = threadIdx.x >> 6, l = threadIdx.x & 63;
  int n = blockIdx.x * 4 + w;
  const bf16_t* r = WpcT + (size_t)n * 1024;
  bf16x8 v1 = *(const bf16x8*)(r + l * 8);
  bf16x8 v2 = *(const bf16x8*)(r + 512 + l * 8);
  float s1 = 0.f, s2 = 0.f;
#pragma unroll
  for (int e = 0; e < 8; ++e) {
    s1 += (float)v1[e] * bpe[l * 8 + e];
    s2 += (float)v2[e] * bpe[512 + l * 8 + e];
  }
#pragma unroll
  for (int off = 32; off; off >>= 1) {
    s1 += __shfl_down(s1, off);
    s2 += __shfl_down(s2, off);
  }
  if (l == 0) { b12[n] = s1 + bpc[n]; b12[4096 + n] = s2; }
}

// ---------- k_ht2: HU/TU = ecb @ W{1,2}T + b12 (2-phase dbuf, counted vmcnt) ----------
__global__ __launch_bounds__(256, 2) void k_ht2(const bf16_t* __restrict__ ecb,
                                                const bf16_t* __restrict__ W1T,
                                                const bf16_t* __restrict__ W2T,
                                                const float* __restrict__ b12,
                                                bf16_t* __restrict__ HU,
                                                bf16_t* __restrict__ TU) {
  __shared__ bf16_t sA[2][128 * 64];
  __shared__ bf16_t sB[2][128 * 64];
  const int t = threadIdx.x, w = t >> 6, l = t & 63;
  const int lrow = l & 15, lkB = (l >> 4) << 4;
  const int n0 = blockIdx.x * 128, m0 = blockIdx.y * 128, z = blockIdx.z;
  const bf16_t* Bw = z ? W2T : W1T;
  const float* bias = b12 + z * 4096;
  bf16_t* dst = z ? TU : HU;

  const int srow = (w << 5) + (l >> 3);
  const int sk = (l & 7) * 8;
  const bf16_t* gA = ecb + (size_t)(m0 + srow) * 512 + sk;
  const bf16_t* gB = Bw + (size_t)(n0 + srow) * 512 + sk;
  const int lofs = (w << 11);

  f32x4 acc[2][8];
#pragma unroll
  for (int rf = 0; rf < 2; ++rf)
#pragma unroll
    for (int cf = 0; cf < 8; ++cf) { f32x4 zz = {0.f, 0.f, 0.f, 0.f}; acc[rf][cf] = zz; }

#pragma unroll
  for (int i = 0; i < 4; ++i) gload16(gA + i * 4096, &sA[0][lofs] + i * 512);
#pragma unroll
  for (int i = 0; i < 4; ++i) gload16(gB + i * 4096, &sB[0][lofs] + i * 512);

#pragma unroll 1
  for (int tt = 0; tt < 8; ++tt) {
    const int cur = tt & 1;
    if (tt < 7) {
      const int kk = (tt + 1) * 64;
#pragma unroll
      for (int i = 0; i < 4; ++i) gload16(gA + i * 4096 + kk, &sA[cur ^ 1][lofs] + i * 512);
#pragma unroll
      for (int i = 0; i < 4; ++i) gload16(gB + i * 4096 + kk, &sB[cur ^ 1][lofs] + i * 512);
      asm volatile("s_waitcnt vmcnt(8)" ::: "memory");
    } else {
      asm volatile("s_waitcnt vmcnt(0)" ::: "memory");
    }
    __syncthreads();
#pragma unroll
    for (int ks = 0; ks < 2; ++ks) {
      bf16x8 af[2], bfr[8];
#pragma unroll
      for (int rf = 0; rf < 2; ++rf) {
        int row = w * 32 + rf * 16 + lrow;
        af[rf] = *(const bf16x8*)((const char*)&sA[cur][0] + (row << 7) + (ks << 6) + lkB);
      }
#pragma unroll
      for (int cf = 0; cf < 8; ++cf) {
        int col = cf * 16 + lrow;
        bfr[cf] = *(const bf16x8*)((const char*)&sB[cur][0] + (col << 7) + (ks << 6) + lkB);
      }
#pragma unroll
      for (int rf = 0; rf < 2; ++rf)
#pragma unroll
        for (int cf = 0; cf < 8; ++cf)
          acc[rf][cf] = mfma16(af[rf], bfr[cf], acc[rf][cf]);
    }
    __syncthreads();
  }
#pragma unroll
  for (int cf = 0; cf < 8; ++cf) {
    float bb = bias[n0 + cf * 16 + lrow];
#pragma unroll
    for (int rf = 0; rf < 2; ++rf)
#pragma unroll
      for (int r = 0; r < 4; ++r) {
        int row = m0 + w * 32 + rf * 16 + ((l >> 4) << 2) + r;
        dst[(size_t)row * 4096 + n0 + cf * 16 + lrow] = (bf16_t)(acc[rf][cf][r] + bb);
      }
  }
}

// ---------- k_out4: DMA-staged streaming GEMM + fused epilogue ----------
// Block = 64 pairs x K=4096 (64 chunks of 64). HU/TU gathers and vis stream
// staged via global_load_lds (per-lane swizzled SOURCE, linear LDS dest);
// weights issued BEFORE DMAs each chunk so their waits never drain the queue.
__global__ __launch_bounds__(256, 2) void k_out4(
    const bf16_t* __restrict__ HU, const bf16_t* __restrict__ TU,
    const bf16_t* __restrict__ WcatT, const bf16_t* __restrict__ WvcatT,
    const float* __restrict__ bcv,
    const int* __restrict__ pair_idx, const int* __restrict__ pair_pred,
    const float* __restrict__ vis, const float* __restrict__ freq,
    float* __restrict__ out) {
  __shared__ bf16_t sHU[2][4096];   // [64 rows][64 k] bf16, 8 KB each buf
  __shared__ bf16_t sTU[2][4096];
  __shared__ float  sV[2][4096];    // [64 rows][64 k] f32, 16 KB each buf
  __shared__ int sR0[64], sR1[64];

  const int t = threadIdx.x, w = t >> 6, l = t & 63;
  const int lrow = l & 15, lseg = l >> 4;
  const int p0 = blockIdx.x * 64;

  if (t < 64) { sR0[t] = pair_idx[(p0 + t) * 2]; sR1[t] = pair_idx[(p0 + t) * 2 + 1]; }
  __syncthreads();

  // staging sources (per-lane; XOR pre-swizzled so linear LDS + swizzled read match)
  const bf16_t* srcH[2]; const bf16_t* srcT[2]; const float* srcV[4];
  int ldsH[2], ldsV[4];
#pragma unroll
  for (int i = 0; i < 2; ++i) {
    int row = w * 16 + i * 8 + (l >> 3);
    int u = (l & 7) ^ (row & 7);
    srcH[i] = HU + (size_t)sR0[row] * 4096 + u * 8;
    srcT[i] = TU + (size_t)sR1[row] * 4096 + u * 8;
    ldsH[i] = (w * 2 + i) * 512 + l * 8;     // element offset
  }
#pragma unroll
  for (int i = 0; i < 4; ++i) {
    int row = w * 16 + i * 4 + (l >> 4);
    int u = (l & 15) ^ (row & 15);
    srcV[i] = vis + (size_t)(p0 + row) * 4096 + u * 4;
    ldsV[i] = (w * 4 + i) * 256 + l * 4;     // float offset
  }

  // weight fragment bases (per-lane, L2-hot)
  const bf16_t* wcb = WcatT + (size_t)lrow * 4096 + lseg * 8;
  const bf16_t* wvb = WvcatT + (size_t)lrow * 4096 + lseg * 8;

  // A-frag LDS read offsets
  const int rowa = w * 16 + lrow;
  int huOff[2], vOff[2][2];
#pragma unroll
  for (int ks = 0; ks < 2; ++ks) {
    huOff[ks] = rowa * 64 + (((ks * 4 + lseg) ^ (rowa & 7)) * 8);          // bf16 elems
#pragma unroll
    for (int h = 0; h < 2; ++h)
      vOff[ks][h] = rowa * 64 + (((ks * 8 + lseg * 2 + h) ^ (rowa & 15)) * 4); // floats
  }

  f32x4 acc[4];
#pragma unroll
  for (int cf = 0; cf < 4; ++cf) { f32x4 z = {0.f, 0.f, 0.f, 0.f}; acc[cf] = z; }

  // prologue: stage chunk 0 into buf 0
#pragma unroll
  for (int i = 0; i < 2; ++i) { gload16(srcH[i], &sHU[0][ldsH[i]]); gload16(srcT[i], &sTU[0][ldsH[i]]); }
#pragma unroll
  for (int i = 0; i < 4; ++i) gload16(srcV[i], &sV[0][ldsV[i]]);

#pragma unroll 1
  for (int tt = 0; tt < 64; ++tt) {
    const int cur = tt & 1;
    const int kb = tt * 64;
    // (a) weight frags for THIS chunk (issued first -> FIFO ahead of DMAs)
    bf16x8 wf[2][4], wg[2][4];
#pragma unroll
    for (int ks = 0; ks < 2; ++ks)
#pragma unroll
      for (int cf = 0; cf < 4; ++cf) {
        wf[ks][cf] = *(const bf16x8*)(wcb + (size_t)cf * 65536 + kb + ks * 32);
        wg[ks][cf] = *(const bf16x8*)(wvb + (size_t)cf * 65536 + kb + ks * 32);
      }
    __builtin_amdgcn_sched_barrier(0);
    // (b) stage chunk tt+1 into buf[cur^1]
    if (tt < 63) {
      const int nx = cur ^ 1, ke = (tt + 1) * 64;
#pragma unroll
      for (int i = 0; i < 2; ++i) {
        gload16(srcH[i] + ke, &sHU[nx][ldsH[i]]);
        gload16(srcT[i] + ke, &sTU[nx][ldsH[i]]);
      }
#pragma unroll
      for (int i = 0; i < 4; ++i) gload16(srcV[i] + ke, &sV[nx][ldsV[i]]);
      __builtin_amdgcn_sched_barrier(0);
      // (c) wait for chunk tt's DMAs (issued last iter; oldest in FIFO).
      // outstanding now = 16 weights + 8 new DMAs = 24.
      asm volatile("s_waitcnt vmcnt(24)" ::: "memory");
    } else {
      asm volatile("s_waitcnt vmcnt(16)" ::: "memory");
    }
    __syncthreads();
    // (d) compute chunk tt
#pragma unroll
    for (int ks = 0; ks < 2; ++ks) {
      bf16x8 hv = *(const bf16x8*)(&sHU[cur][huOff[ks]]);
      bf16x8 tv = *(const bf16x8*)(&sTU[cur][huOff[ks]]);
      bf16x8 af;
#pragma unroll
      for (int e = 0; e < 8; ++e)
        af[e] = (bf16_t)fmaxf((float)hv[e] + (float)tv[e], 0.f);
#pragma unroll
      for (int cf = 0; cf < 4; ++cf) acc[cf] = mfma16(af, wf[ks][cf], acc[cf]);
    }
#pragma unroll
    for (int ks = 0; ks < 2; ++ks) {
      f32x4 v0 = *(const f32x4*)(&sV[cur][vOff[ks][0]]);
      f32x4 v1 = *(const f32x4*)(&sV[cur][vOff[ks][1]]);
      bf16x8 af;
      af[0] = (bf16_t)v0[0]; af[1] = (bf16_t)v0[1]; af[2] = (bf16_t)v0[2]; af[3] = (bf16_t)v0[3];
      af[4] = (bf16_t)v1[0]; af[5] = (bf16_t)v1[1]; af[6] = (bf16_t)v1[2]; af[7] = (bf16_t)v1[3];
#pragma unroll
      for (int cf = 0; cf < 4; ++cf) acc[cf] = mfma16(af, wg[ks][cf], acc[cf]);
    }
    __syncthreads();   // protect buf[cur] before it is restaged next iter
  }

  // epilogue: acc -> LDS (reuse sV[0]), then per-pair freq/logsumexp
  float* sF = &sV[0][0];
#pragma unroll
  for (int cf = 0; cf < 4; ++cf) {
    float bb = bcv[cf * 16 + lrow];
#pragma unroll
    for (int r = 0; r < 4; ++r) {
      int row = w * 16 + lseg * 4 + r;
      sF[row * 64 + cf * 16 + lrow] = acc[cf][r] + bb;
    }
  }
  __syncthreads();
  if (t < 64) {
    int p = p0 + t;
    const float* f = freq + ((size_t)pair_pred[p * 2] * 151 + pair_pred[p * 2 + 1]) * 51;
    const float* rowv = sF + t * 64;
    float e1 = 0.f, e2 = 0.f, e3 = 0.f;
#pragma unroll
    for (int c = 0; c < 15; ++c) {
      float fb = f[GEO_c[c]]; e1 += expf(fb);
      out[(size_t)p * 15 + c] = rowv[c] + fb;
    }
#pragma unroll
    for (int c = 0; c < 11; ++c) {
      float fb = f[POS_c[c]]; e2 += expf(fb);
      out[491520 + (size_t)p * 11 + c] = rowv[15 + c] + fb;
    }
#pragma unroll
    for (int c = 0; c < 24; ++c) {
      float fb = f[SEM_c[c]]; e3 += expf(fb);
      out[851968 + (size_t)p * 24 + c] = rowv[26 + c] + fb;
    }
    out[1638400 + (size_t)p * 4 + 0] = rowv[50] + f[0];
    out[1638400 + (size_t)p * 4 + 1] = rowv[51] + logf(e1);
    out[1638400 + (size_t)p * 4 + 2] = rowv[52] + logf(e2);
    out[1638400 + (size_t)p * 4 + 3] = rowv[53] + logf(e3);
  }
}

extern "C" void kernel_launch(void* const* d_in, const int* in_sizes, int n_in,
                              void* d_out, int out_size, void* d_ws, size_t ws_size,
                              hipStream_t stream) {
  const float* edge_ctx  = (const float*)d_in[0];
  const int*   pair_idx  = (const int*)d_in[1];
  const float* vis_rep   = (const float*)d_in[2];
  const int*   pair_pred = (const int*)d_in[3];
  const float* Wpe = (const float*)d_in[4];
  const float* bpe = (const float*)d_in[5];
  const float* Wpc = (const float*)d_in[6];
  const float* bpc = (const float*)d_in[7];
  const float* Wc1 = (const float*)d_in[8];  const float* bc1 = (const float*)d_in[9];
  const float* Wc2 = (const float*)d_in[10]; const float* bc2 = (const float*)d_in[11];
  const float* Wc3 = (const float*)d_in[12]; const float* bc3 = (const float*)d_in[13];
  const float* Wcs = (const float*)d_in[14]; const float* bcs = (const float*)d_in[15];
  const float* Wv1 = (const float*)d_in[16]; const float* bv1 = (const float*)d_in[17];
  const float* Wv2 = (const float*)d_in[18]; const float* bv2 = (const float*)d_in[19];
  const float* Wv3 = (const float*)d_in[20]; const float* bv3 = (const float*)d_in[21];
  const float* Wvs = (const float*)d_in[22]; const float* bvs = (const float*)d_in[23];
  const float* freq = (const float*)d_in[24];
  float* out = (float*)d_out;

  char* ws = (char*)d_ws;
  bf16_t* WpcT   = (bf16_t*)(ws + 0);           //  8388608
  bf16_t* W1T    = (bf16_t*)(ws + 8388608);     //  4194304
  bf16_t* W2T    = (bf16_t*)(ws + 12582912);    //  4194304
  bf16_t* ecb    = (bf16_t*)(ws + 16777216);    //  8388608
  bf16_t* WcatT  = (bf16_t*)(ws + 33554432);    //   524288
  bf16_t* WvcatT = (bf16_t*)(ws + 34078720);    //   524288
  float*  bcv    = (float*)(ws + 34603008);     //     4096 (pad)
  float*  b12    = (float*)(ws + 34607104);     //    32768
  bf16_t* HU     = (bf16_t*)(ws + 34639872);    // 67108864
  bf16_t* TU     = (bf16_t*)(ws + 101748736);   // 67108864  -> end 168857600

  k_transpose<<<dim3(64, 16), 256, 0, stream>>>(Wpc, WpcT, 1024, 4096);
  k_pack_cat<<<64, 256, 0, stream>>>(Wc1, Wc2, Wc3, Wcs, Wv1, Wv2, Wv3, Wvs,
                                     bc1, bc2, bc3, bcs, bv1, bv2, bv3, bvs,
                                     WcatT, WvcatT, bcv);
  k_ec<<<2048, 256, 0, stream>>>(edge_ctx, ecb);
  k_w12<<<dim3(4, 32, 2), 256, 0, stream>>>(WpcT, Wpe, W1T, W2T);
  k_bias<<<1024, 256, 0, stream>>>(WpcT, bpe, bpc, b12);
  k_ht2<<<dim3(32, 64, 2), 256, 0, stream>>>(ecb, W1T, W2T, b12, HU, TU);
  k_out4<<<512, 256, 0, stream>>>(HU, TU, WcatT, WvcatT, bcv,
                                  pair_idx, pair_pred, vis_rep, freq, out);
}

// Round 8
// 357.008 us; speedup vs baseline: 1.5948x; 1.3920x over previous
//
#include <hip/hip_runtime.h>
#include <hip/hip_bf16.h>

typedef __bf16 bf16_t;
typedef __bf16 bf16x8 __attribute__((ext_vector_type(8)));
typedef __bf16 bf16x4 __attribute__((ext_vector_type(4)));
typedef float f32x4 __attribute__((ext_vector_type(4)));

#define DI __device__ __forceinline__

DI f32x4 mfma16(bf16x8 a, bf16x8 b, f32x4 c) {
  return __builtin_amdgcn_mfma_f32_16x16x32_bf16(a, b, c, 0, 0, 0);
}

DI void gload16(const void* g, void* l) {
  __builtin_amdgcn_global_load_lds(
      (const __attribute__((address_space(1))) unsigned int*)g,
      (__attribute__((address_space(3))) unsigned int*)l, 16, 0, 0);
}

__constant__ int GEO_c[15] = {1,2,3,4,5,6,8,10,22,23,29,31,32,33,43};
__constant__ int POS_c[11] = {9,16,17,20,27,30,36,42,48,49,50};
__constant__ int SEM_c[24] = {7,11,12,13,14,15,18,19,21,24,25,26,28,34,35,37,38,39,40,41,44,45,46,47};

// ---------- prep: transpose f32 Wpc [1024][4096] -> bf16 WpcT [4096][1024] ----------
__global__ void k_transpose(const float* __restrict__ src, bf16_t* __restrict__ dst,
                            int K, int N) {
  __shared__ float s[64][65];
  int n0 = blockIdx.x * 64, k0 = blockIdx.y * 64;
  int t = threadIdx.x;
#pragma unroll
  for (int i = 0; i < 4; ++i) {
    int idx = t + i * 256; int kr = idx >> 4, seg = idx & 15;
    float4 v = *(const float4*)(src + (size_t)(k0 + kr) * N + n0 + seg * 4);
    s[kr][seg * 4 + 0] = v.x; s[kr][seg * 4 + 1] = v.y;
    s[kr][seg * 4 + 2] = v.z; s[kr][seg * 4 + 3] = v.w;
  }
  __syncthreads();
#pragma unroll
  for (int i = 0; i < 4; ++i) {
    int idx = t + i * 256; int nr = idx >> 4, seg = idx & 15;
    bf16x4 h;
    h[0] = (bf16_t)s[seg * 4 + 0][nr]; h[1] = (bf16_t)s[seg * 4 + 1][nr];
    h[2] = (bf16_t)s[seg * 4 + 2][nr]; h[3] = (bf16_t)s[seg * 4 + 3][nr];
    *(bf16x4*)(dst + (size_t)(n0 + nr) * K + k0 + seg * 4) = h;
  }
}

// ---------- prep: pack Wc*/Wv* into [64][4096] bf16 (cols 54..63 zero), bcv ----------
DI void cat_map(int j, int& which, int& sub, int& nc) {
  if (j < 15)      { which = 0; sub = j;      nc = 15; }
  else if (j < 26) { which = 1; sub = j - 15; nc = 11; }
  else if (j < 50) { which = 2; sub = j - 26; nc = 24; }
  else if (j < 54) { which = 3; sub = j - 50; nc = 4;  }
  else             { which = 4; sub = 0;      nc = 1;  }
}

__global__ void k_pack_cat(const float* __restrict__ Wc1, const float* __restrict__ Wc2,
                           const float* __restrict__ Wc3, const float* __restrict__ Wcs,
                           const float* __restrict__ Wv1, const float* __restrict__ Wv2,
                           const float* __restrict__ Wv3, const float* __restrict__ Wvs,
                           const float* __restrict__ bc1, const float* __restrict__ bc2,
                           const float* __restrict__ bc3, const float* __restrict__ bcs,
                           const float* __restrict__ bv1, const float* __restrict__ bv2,
                           const float* __restrict__ bv3, const float* __restrict__ bvs,
                           bf16_t* __restrict__ WcatT, bf16_t* __restrict__ WvcatT,
                           float* __restrict__ bcv) {
  int j = blockIdx.x, t = threadIdx.x;
  int which, sub, nc; cat_map(j, which, sub, nc);
  const float* Wc = which == 0 ? Wc1 : which == 1 ? Wc2 : which == 2 ? Wc3 : Wcs;
  const float* Wv = which == 0 ? Wv1 : which == 1 ? Wv2 : which == 2 ? Wv3 : Wvs;
  for (int i = 0; i < 16; ++i) {
    int k = t + i * 256;
    float vc = 0.f, vv = 0.f;
    if (which < 4) { vc = Wc[(size_t)k * nc + sub]; vv = Wv[(size_t)k * nc + sub]; }
    WcatT[(size_t)j * 4096 + k] = (bf16_t)vc;
    WvcatT[(size_t)j * 4096 + k] = (bf16_t)vv;
  }
  if (t == 0) {
    float b = 0.f;
    if (which < 4) {
      const float* bc = which == 0 ? bc1 : which == 1 ? bc2 : which == 2 ? bc3 : bcs;
      const float* bv = which == 0 ? bv1 : which == 1 ? bv2 : which == 2 ? bv3 : bvs;
      b = bc[sub] + bv[sub];
    }
    bcv[j] = b;
  }
}

// ---------- prep: ec f32 -> ecb bf16 ----------
__global__ __launch_bounds__(256) void k_ec(const float* __restrict__ ec,
                                            bf16_t* __restrict__ ecb) {
  size_t i = ((size_t)blockIdx.x * 256 + threadIdx.x) * 8;
  float4 a = *(const float4*)(ec + i), b = *(const float4*)(ec + i + 4);
  bf16x8 h;
  h[0] = (bf16_t)a.x; h[1] = (bf16_t)a.y; h[2] = (bf16_t)a.z; h[3] = (bf16_t)a.w;
  h[4] = (bf16_t)b.x; h[5] = (bf16_t)b.y; h[6] = (bf16_t)b.z; h[7] = (bf16_t)b.w;
  *(bf16x8*)(ecb + i) = h;
}

// ---------- prep: W1T[n][k] = sum_j WpcT[n, joff+j] * Wpe[k, joff+j] ----------
__global__ __launch_bounds__(256) void k_w12(const bf16_t* __restrict__ WpcT,
                                             const float* __restrict__ Wpe,
                                             bf16_t* __restrict__ W1T,
                                             bf16_t* __restrict__ W2T) {
  __shared__ bf16_t sA[128 * 64];
  __shared__ bf16_t sB[128 * 64];
  const int t = threadIdx.x, w = t >> 6, l = t & 63;
  const int lrow = l & 15, lkB = (l >> 4) << 4;
  const int k0 = blockIdx.x * 128, n0 = blockIdx.y * 128;
  const int joff = blockIdx.z * 512;
  bf16_t* dst = blockIdx.z ? W2T : W1T;

  f32x4 acc[2][8];
#pragma unroll
  for (int rf = 0; rf < 2; ++rf)
#pragma unroll
    for (int cf = 0; cf < 8; ++cf) { f32x4 z = {0.f, 0.f, 0.f, 0.f}; acc[rf][cf] = z; }

  for (int jj = 0; jj < 512; jj += 64) {
    __syncthreads();
#pragma unroll
    for (int i = 0; i < 4; ++i) {
      int row = (t >> 3) + (i << 5), seg = t & 7;
      bf16x8 v = *(const bf16x8*)(WpcT + (size_t)(n0 + row) * 1024 + joff + jj + seg * 8);
      *(bf16x8*)((char*)sA + (row << 7) + ((seg << 4) ^ ((row & 7) << 4))) = v;
    }
#pragma unroll
    for (int i = 0; i < 8; ++i) {
      int idx = t + i * 256; int row = idx >> 4, seg = idx & 15;
      float4 v = *(const float4*)(Wpe + (size_t)(k0 + row) * 1024 + joff + jj + seg * 4);
      bf16x4 h; h[0] = (bf16_t)v.x; h[1] = (bf16_t)v.y; h[2] = (bf16_t)v.z; h[3] = (bf16_t)v.w;
      *(bf16x4*)((char*)sB + (row << 7) + ((seg << 3) ^ ((row & 7) << 4))) = h;
    }
    __syncthreads();
#pragma unroll
    for (int ks = 0; ks < 2; ++ks) {
      bf16x8 af[2], bfr[8];
#pragma unroll
      for (int rf = 0; rf < 2; ++rf) {
        int row = w * 32 + rf * 16 + lrow;
        af[rf] = *(const bf16x8*)((const char*)sA + (row << 7) + (((ks << 6) | lkB) ^ ((row & 7) << 4)));
      }
#pragma unroll
      for (int cf = 0; cf < 8; ++cf) {
        int col = cf * 16 + lrow;
        bfr[cf] = *(const bf16x8*)((const char*)sB + (col << 7) + (((ks << 6) | lkB) ^ ((col & 7) << 4)));
      }
#pragma unroll
      for (int rf = 0; rf < 2; ++rf)
#pragma unroll
        for (int cf = 0; cf < 8; ++cf)
          acc[rf][cf] = mfma16(af[rf], bfr[cf], acc[rf][cf]);
    }
  }
#pragma unroll
  for (int cf = 0; cf < 8; ++cf)
#pragma unroll
    for (int rf = 0; rf < 2; ++rf)
#pragma unroll
      for (int r = 0; r < 4; ++r) {
        int nrow = n0 + w * 32 + rf * 16 + ((l >> 4) << 2) + r;
        dst[(size_t)nrow * 512 + k0 + cf * 16 + lrow] = (bf16_t)acc[rf][cf][r];
      }
}

// ---------- prep: b12 ----------
__global__ __launch_bounds__(256) void k_bias(const bf16_t* __restrict__ WpcT,
                                              const float* __restrict__ bpe,
                                              const float* __restrict__ bpc,
                                              float* __restrict__ b12) {
  int w = threadIdx.x >> 6, l = threadIdx.x & 63;
  int n = blockIdx.x * 4 + w;
  const bf16_t* r = WpcT + (size_t)n * 1024;
  bf16x8 v1 = *(const bf16x8*)(r + l * 8);
  bf16x8 v2 = *(const bf16x8*)(r + 512 + l * 8);
  float s1 = 0.f, s2 = 0.f;
#pragma unroll
  for (int e = 0; e < 8; ++e) {
    s1 += (float)v1[e] * bpe[l * 8 + e];
    s2 += (float)v2[e] * bpe[512 + l * 8 + e];
  }
#pragma unroll
  for (int off = 32; off; off >>= 1) {
    s1 += __shfl_down(s1, off);
    s2 += __shfl_down(s2, off);
  }
  if (l == 0) { b12[n] = s1 + bpc[n]; b12[4096 + n] = s2; }
}

// ---------- k_ht2: HU/TU = ecb @ W{1,2}T + b12 (2-phase dbuf, counted vmcnt) ----------
__global__ __launch_bounds__(256, 2) void k_ht2(const bf16_t* __restrict__ ecb,
                                                const bf16_t* __restrict__ W1T,
                                                const bf16_t* __restrict__ W2T,
                                                const float* __restrict__ b12,
                                                bf16_t* __restrict__ HU,
                                                bf16_t* __restrict__ TU) {
  __shared__ bf16_t sA[2][128 * 64];
  __shared__ bf16_t sB[2][128 * 64];
  const int t = threadIdx.x, w = t >> 6, l = t & 63;
  const int lrow = l & 15, lkB = (l >> 4) << 4;
  const int n0 = blockIdx.x * 128, m0 = blockIdx.y * 128, z = blockIdx.z;
  const bf16_t* Bw = z ? W2T : W1T;
  const float* bias = b12 + z * 4096;
  bf16_t* dst = z ? TU : HU;

  const int srow = (w << 5) + (l >> 3);
  const int sk = (l & 7) * 8;
  const bf16_t* gA = ecb + (size_t)(m0 + srow) * 512 + sk;
  const bf16_t* gB = Bw + (size_t)(n0 + srow) * 512 + sk;
  const int lofs = (w << 11);

  f32x4 acc[2][8];
#pragma unroll
  for (int rf = 0; rf < 2; ++rf)
#pragma unroll
    for (int cf = 0; cf < 8; ++cf) { f32x4 zz = {0.f, 0.f, 0.f, 0.f}; acc[rf][cf] = zz; }

#pragma unroll
  for (int i = 0; i < 4; ++i) gload16(gA + i * 4096, &sA[0][lofs] + i * 512);
#pragma unroll
  for (int i = 0; i < 4; ++i) gload16(gB + i * 4096, &sB[0][lofs] + i * 512);

#pragma unroll 1
  for (int tt = 0; tt < 8; ++tt) {
    const int cur = tt & 1;
    if (tt < 7) {
      const int kk = (tt + 1) * 64;
#pragma unroll
      for (int i = 0; i < 4; ++i) gload16(gA + i * 4096 + kk, &sA[cur ^ 1][lofs] + i * 512);
#pragma unroll
      for (int i = 0; i < 4; ++i) gload16(gB + i * 4096 + kk, &sB[cur ^ 1][lofs] + i * 512);
      asm volatile("s_waitcnt vmcnt(8)" ::: "memory");
    } else {
      asm volatile("s_waitcnt vmcnt(0)" ::: "memory");
    }
    __syncthreads();
#pragma unroll
    for (int ks = 0; ks < 2; ++ks) {
      bf16x8 af[2], bfr[8];
#pragma unroll
      for (int rf = 0; rf < 2; ++rf) {
        int row = w * 32 + rf * 16 + lrow;
        af[rf] = *(const bf16x8*)((const char*)&sA[cur][0] + (row << 7) + (ks << 6) + lkB);
      }
#pragma unroll
      for (int cf = 0; cf < 8; ++cf) {
        int col = cf * 16 + lrow;
        bfr[cf] = *(const bf16x8*)((const char*)&sB[cur][0] + (col << 7) + (ks << 6) + lkB);
      }
#pragma unroll
      for (int rf = 0; rf < 2; ++rf)
#pragma unroll
        for (int cf = 0; cf < 8; ++cf)
          acc[rf][cf] = mfma16(af[rf], bfr[cf], acc[rf][cf]);
    }
    __syncthreads();
  }
#pragma unroll
  for (int cf = 0; cf < 8; ++cf) {
    float bb = bias[n0 + cf * 16 + lrow];
#pragma unroll
    for (int rf = 0; rf < 2; ++rf)
#pragma unroll
      for (int r = 0; r < 4; ++r) {
        int row = m0 + w * 32 + rf * 16 + ((l >> 4) << 2) + r;
        dst[(size_t)row * 4096 + n0 + cf * 16 + lrow] = (bf16_t)(acc[rf][cf][r] + bb);
      }
  }
}

// ---------- k_out5: DMA-staged gathers + DMA-staged (deduped) weights ----------
// Block = 64 pairs x K=4096 (64 chunks). HU/TU gathers AND Wcat/Wvcat chunks
// staged once per block via global_load_lds (swizzled src, linear dest);
// vis is a coalesced per-lane register stream. Weight traffic deduped 4x vs k_out4.
__global__ __launch_bounds__(256, 2) void k_out5(
    const bf16_t* __restrict__ HU, const bf16_t* __restrict__ TU,
    const bf16_t* __restrict__ WcatT, const bf16_t* __restrict__ WvcatT,
    const float* __restrict__ bcv,
    const int* __restrict__ pair_idx, const int* __restrict__ pair_pred,
    const float* __restrict__ vis, const float* __restrict__ freq,
    float* __restrict__ out) {
  __shared__ bf16_t sHU[2][4096];   // [64 rows][64 k] bf16, 8 KB per buf
  __shared__ bf16_t sTU[2][4096];
  __shared__ bf16_t sW[2][8192];    // [cv][64 cols][64 k] bf16, 16 KB per buf
  __shared__ int sR0[64], sR1[64];

  const int t = threadIdx.x, w = t >> 6, l = t & 63;
  const int lrow = l & 15, lseg = l >> 4;
  const int p0 = blockIdx.x * 64;

  if (t < 64) { sR0[t] = pair_idx[(p0 + t) * 2]; sR1[t] = pair_idx[(p0 + t) * 2 + 1]; }
  __syncthreads();

  // ---- gather staging sources (per-lane, XOR pre-swizzled source) ----
  const bf16_t* srcH[2]; const bf16_t* srcT[2];
  int ldsH[2];
#pragma unroll
  for (int i = 0; i < 2; ++i) {
    int row = w * 16 + i * 8 + (l >> 3);
    int u = (l & 7) ^ (row & 7);
    srcH[i] = HU + (size_t)sR0[row] * 4096 + u * 8;
    srcT[i] = TU + (size_t)sR1[row] * 4096 + u * 8;
    ldsH[i] = (w * 2 + i) * 512 + l * 8;
  }
  // ---- weight staging sources (4 per thread covering 16 KB/chunk) ----
  const bf16_t* srcW[4];
  int ldsW[4];
#pragma unroll
  for (int i = 0; i < 4; ++i) {
    int f = i * 256 + t;              // 0..1023 16B-chunks
    int cv = f >> 9, col = (f >> 3) & 63, u = f & 7;
    const bf16_t* base = cv ? WvcatT : WcatT;
    srcW[i] = base + (size_t)col * 4096 + (u ^ (col & 7)) * 8;
    ldsW[i] = f * 8;
  }

  // ---- vis per-lane stream (A-fragment layout: row=lrow of this wave) ----
  const float* vb = vis + (size_t)(p0 + w * 16 + lrow) * 4096 + lseg * 8;

  // ---- LDS read offsets ----
  const int rowa = w * 16 + lrow;
  int huOff[2], wOff[2];
#pragma unroll
  for (int ks = 0; ks < 2; ++ks) {
    huOff[ks] = rowa * 64 + (((ks * 4 + lseg) ^ (rowa & 7)) * 8);          // bf16 elems
    wOff[ks] = lrow * 128 + (((ks * 4 + lseg) ^ (lrow & 7)) * 16);          // bytes
  }

  f32x4 acc[4];
#pragma unroll
  for (int cf = 0; cf < 4; ++cf) { f32x4 z = {0.f, 0.f, 0.f, 0.f}; acc[cf] = z; }

  // prologue: stage chunk 0 into buf 0
#pragma unroll
  for (int i = 0; i < 2; ++i) { gload16(srcH[i], &sHU[0][ldsH[i]]); gload16(srcT[i], &sTU[0][ldsH[i]]); }
#pragma unroll
  for (int i = 0; i < 4; ++i) gload16(srcW[i], &sW[0][ldsW[i]]);

#pragma unroll 1
  for (int tt = 0; tt < 64; ++tt) {
    const int cur = tt & 1;
    const int kb = tt * 64;
    // (a) vis loads for THIS chunk (registers, coalesced)
    f32x4 vv[4];
#pragma unroll
    for (int ks = 0; ks < 2; ++ks) {
      vv[ks * 2 + 0] = *(const f32x4*)(vb + kb + ks * 32);
      vv[ks * 2 + 1] = *(const f32x4*)(vb + kb + ks * 32 + 4);
    }
    __builtin_amdgcn_sched_barrier(0);
    // (b) stage chunk tt+1 (8 DMAs/thread)
    if (tt < 63) {
      const int nx = cur ^ 1, ke = (tt + 1) * 64;
#pragma unroll
      for (int i = 0; i < 2; ++i) {
        gload16(srcH[i] + ke, &sHU[nx][ldsH[i]]);
        gload16(srcT[i] + ke, &sTU[nx][ldsH[i]]);
      }
#pragma unroll
      for (int i = 0; i < 4; ++i) gload16(srcW[i] + ke, &sW[nx][ldsW[i]]);
      __builtin_amdgcn_sched_barrier(0);
      // outstanding: vis(t)=4 + DMA(t+1)=8 -> wait retires DMA(t)
      asm volatile("s_waitcnt vmcnt(12)" ::: "memory");
    } else {
      asm volatile("s_waitcnt vmcnt(4)" ::: "memory");   // retire DMA(63); vis still in flight
    }
    __syncthreads();
    // (c) compute chunk tt
#pragma unroll
    for (int ks = 0; ks < 2; ++ks) {
      // P fragment
      bf16x8 hv = *(const bf16x8*)(&sHU[cur][huOff[ks]]);
      bf16x8 tv = *(const bf16x8*)(&sTU[cur][huOff[ks]]);
      bf16x8 af;
#pragma unroll
      for (int e = 0; e < 8; ++e)
        af[e] = (bf16_t)fmaxf((float)hv[e] + (float)tv[e], 0.f);
#pragma unroll
      for (int cf = 0; cf < 4; ++cf) {
        bf16x8 bw = *(const bf16x8*)((const char*)&sW[cur][0] + cf * 2048 + wOff[ks]);
        acc[cf] = mfma16(af, bw, acc[cf]);
      }
      // vis fragment
      f32x4 v0 = vv[ks * 2 + 0], v1 = vv[ks * 2 + 1];
      bf16x8 ag;
      ag[0] = (bf16_t)v0[0]; ag[1] = (bf16_t)v0[1]; ag[2] = (bf16_t)v0[2]; ag[3] = (bf16_t)v0[3];
      ag[4] = (bf16_t)v1[0]; ag[5] = (bf16_t)v1[1]; ag[6] = (bf16_t)v1[2]; ag[7] = (bf16_t)v1[3];
#pragma unroll
      for (int cf = 0; cf < 4; ++cf) {
        bf16x8 bw = *(const bf16x8*)((const char*)&sW[cur][0] + 8192 + cf * 2048 + wOff[ks]);
        acc[cf] = mfma16(ag, bw, acc[cf]);
      }
    }
    __syncthreads();   // protect buf[cur] before restage next iter
  }

  // epilogue: acc -> LDS (reuse sW[0], 16 KB), then per-pair freq/logsumexp
  float* sF = (float*)&sW[0][0];
#pragma unroll
  for (int cf = 0; cf < 4; ++cf) {
    float bb = bcv[cf * 16 + lrow];
#pragma unroll
    for (int r = 0; r < 4; ++r) {
      int row = w * 16 + lseg * 4 + r;
      sF[row * 64 + cf * 16 + lrow] = acc[cf][r] + bb;
    }
  }
  __syncthreads();
  if (t < 64) {
    int p = p0 + t;
    const float* f = freq + ((size_t)pair_pred[p * 2] * 151 + pair_pred[p * 2 + 1]) * 51;
    const float* rowv = sF + t * 64;
    float e1 = 0.f, e2 = 0.f, e3 = 0.f;
#pragma unroll
    for (int c = 0; c < 15; ++c) {
      float fb = f[GEO_c[c]]; e1 += expf(fb);
      out[(size_t)p * 15 + c] = rowv[c] + fb;
    }
#pragma unroll
    for (int c = 0; c < 11; ++c) {
      float fb = f[POS_c[c]]; e2 += expf(fb);
      out[491520 + (size_t)p * 11 + c] = rowv[15 + c] + fb;
    }
#pragma unroll
    for (int c = 0; c < 24; ++c) {
      float fb = f[SEM_c[c]]; e3 += expf(fb);
      out[851968 + (size_t)p * 24 + c] = rowv[26 + c] + fb;
    }
    out[1638400 + (size_t)p * 4 + 0] = rowv[50] + f[0];
    out[1638400 + (size_t)p * 4 + 1] = rowv[51] + logf(e1);
    out[1638400 + (size_t)p * 4 + 2] = rowv[52] + logf(e2);
    out[1638400 + (size_t)p * 4 + 3] = rowv[53] + logf(e3);
  }
}

extern "C" void kernel_launch(void* const* d_in, const int* in_sizes, int n_in,
                              void* d_out, int out_size, void* d_ws, size_t ws_size,
                              hipStream_t stream) {
  const float* edge_ctx  = (const float*)d_in[0];
  const int*   pair_idx  = (const int*)d_in[1];
  const float* vis_rep   = (const float*)d_in[2];
  const int*   pair_pred = (const int*)d_in[3];
  const float* Wpe = (const float*)d_in[4];
  const float* bpe = (const float*)d_in[5];
  const float* Wpc = (const float*)d_in[6];
  const float* bpc = (const float*)d_in[7];
  const float* Wc1 = (const float*)d_in[8];  const float* bc1 = (const float*)d_in[9];
  const float* Wc2 = (const float*)d_in[10]; const float* bc2 = (const float*)d_in[11];
  const float* Wc3 = (const float*)d_in[12]; const float* bc3 = (const float*)d_in[13];
  const float* Wcs = (const float*)d_in[14]; const float* bcs = (const float*)d_in[15];
  const float* Wv1 = (const float*)d_in[16]; const float* bv1 = (const float*)d_in[17];
  const float* Wv2 = (const float*)d_in[18]; const float* bv2 = (const float*)d_in[19];
  const float* Wv3 = (const float*)d_in[20]; const float* bv3 = (const float*)d_in[21];
  const float* Wvs = (const float*)d_in[22]; const float* bvs = (const float*)d_in[23];
  const float* freq = (const float*)d_in[24];
  float* out = (float*)d_out;

  char* ws = (char*)d_ws;
  bf16_t* WpcT   = (bf16_t*)(ws + 0);           //  8388608
  bf16_t* W1T    = (bf16_t*)(ws + 8388608);     //  4194304
  bf16_t* W2T    = (bf16_t*)(ws + 12582912);    //  4194304
  bf16_t* ecb    = (bf16_t*)(ws + 16777216);    //  8388608
  bf16_t* WcatT  = (bf16_t*)(ws + 33554432);    //   524288
  bf16_t* WvcatT = (bf16_t*)(ws + 34078720);    //   524288
  float*  bcv    = (float*)(ws + 34603008);     //     4096 (pad)
  float*  b12    = (float*)(ws + 34607104);     //    32768
  bf16_t* HU     = (bf16_t*)(ws + 34639872);    // 67108864
  bf16_t* TU     = (bf16_t*)(ws + 101748736);   // 67108864  -> end 168857600

  k_transpose<<<dim3(64, 16), 256, 0, stream>>>(Wpc, WpcT, 1024, 4096);
  k_pack_cat<<<64, 256, 0, stream>>>(Wc1, Wc2, Wc3, Wcs, Wv1, Wv2, Wv3, Wvs,
                                     bc1, bc2, bc3, bcs, bv1, bv2, bv3, bvs,
                                     WcatT, WvcatT, bcv);
  k_ec<<<2048, 256, 0, stream>>>(edge_ctx, ecb);
  k_w12<<<dim3(4, 32, 2), 256, 0, stream>>>(WpcT, Wpe, W1T, W2T);
  k_bias<<<1024, 256, 0, stream>>>(WpcT, bpe, bpc, b12);
  k_ht2<<<dim3(32, 64, 2), 256, 0, stream>>>(ecb, W1T, W2T, b12, HU, TU);
  k_out5<<<512, 256, 0, stream>>>(HU, TU, WcatT, WvcatT, bcv,
                                  pair_idx, pair_pred, vis_rep, freq, out);
}